// Round 1
// baseline (1199.356 us; speedup 1.0000x reference)
//
#include <hip/hip_runtime.h>
#include <cstdint>
#include <cmath>
#include <cstddef>

#pragma clang fp contract(off)

#define QMAXF 127.0f

enum {
  S_X = 0, S_WQ, S_WK, S_WV, S_WO, S_BQ, S_BK, S_BV, S_BO,
  S_YQ, S_YK, S_YV, S_PMAX, S_CTX, S_CTXQ1, S_COUNT
};

struct PLA { float m[12]; float c[12]; float a[12]; };

// ---------------- device helpers ----------------

__device__ __forceinline__ int dot4i8(uint32_t a, uint32_t b, int acc) {
  acc += (int)(int8_t)(a)       * (int)(int8_t)(b);
  acc += (int)(int8_t)(a >> 8)  * (int)(int8_t)(b >> 8);
  acc += (int)(int8_t)(a >> 16) * (int)(int8_t)(b >> 16);
  acc += (int)(int8_t)(a >> 24) * (int)(int8_t)(b >> 24);
  return acc;
}

__device__ __forceinline__ float qscale(const unsigned* scal, int slot) {
  // reference: scale = max(maxabs / 127.0, 1e-8)
  return fmaxf(__uint_as_float(scal[slot]) / QMAXF, 1e-8f);
}

// ---------------- tiny kernels ----------------

__global__ void zero_scal_kernel(unsigned* s) {
  if (threadIdx.x < 16) s[threadIdx.x] = 0u;
}

__global__ __launch_bounds__(256) void maxabs_kernel(const float* __restrict__ x, int n,
                                                     unsigned* __restrict__ slot) {
  float m = 0.0f;
  for (int i = blockIdx.x * 256 + threadIdx.x; i < n; i += gridDim.x * 256)
    m = fmaxf(m, fabsf(x[i]));
  for (int off = 32; off > 0; off >>= 1) m = fmaxf(m, __shfl_xor(m, off, 64));
  __shared__ float red[4];
  int lane = threadIdx.x & 63, w = threadIdx.x >> 6;
  if (lane == 0) red[w] = m;
  __syncthreads();
  if (threadIdx.x == 0) {
    float mm = fmaxf(fmaxf(red[0], red[1]), fmaxf(red[2], red[3]));
    atomicMax(slot, __float_as_uint(mm));
  }
}

__global__ __launch_bounds__(256) void quant_kernel(const float* __restrict__ x,
                                                    int8_t* __restrict__ q, int n,
                                                    const unsigned* __restrict__ scal, int slot) {
  int i = blockIdx.x * 256 + threadIdx.x;
  if (i >= n) return;
  float s = qscale(scal, slot);
  float t = fminf(fmaxf(rintf(x[i] / s), -127.0f), 127.0f);
  q[i] = (int8_t)t;
}

// Y [B*S][768] -> q in head layout [(b*12+h)][512][64]
__global__ __launch_bounds__(256) void quant_heads_kernel(const float* __restrict__ Y,
                                                          int8_t* __restrict__ q,
                                                          const unsigned* __restrict__ scal, int slot) {
  int i = blockIdx.x * 256 + threadIdx.x;  // flat [b][h][s][d], total 3145728
  float s = qscale(scal, slot);
  int d = i & 63;
  int sidx = (i >> 6) & 511;
  int bh = i >> 15;          // b*12 + h
  int h = bh % 12;
  int b = bh / 12;
  int src = (b * 512 + sidx) * 768 + h * 64 + d;
  float t = fminf(fmaxf(rintf(Y[src] / s), -127.0f), 127.0f);
  q[i] = (int8_t)t;
}

__global__ void qbias_kernel(const float* __restrict__ b, float* __restrict__ qb,
                             const unsigned* __restrict__ scal, int slotX, int slotW, int slotB) {
  int j = blockIdx.x * 256 + threadIdx.x;
  if (j >= 768) return;
  float in_scale = __uint_as_float(scal[slotX]) / QMAXF;   // no clamp (reference)
  float w_scale  = __uint_as_float(scal[slotW]) / QMAXF;
  float bias_scale = in_scale * w_scale;
  float tmax = __uint_as_float(scal[slotB]) / bias_scale;
  float st = fmaxf(tmax / QMAXF, 1e-8f);
  float t = b[j] / bias_scale;
  float qv = fminf(fmaxf(rintf(t / st), -127.0f), 127.0f) * st;
  qb[j] = qv * bias_scale;
}

// ---------------- int8 GEMM:  C[M][N] = (A[M][K] . B[N][K]^T) * sA*sB + bias[N] ----------------

__global__ __launch_bounds__(256) void gemm_i8_kernel(const int8_t* __restrict__ A,
                                                      const int8_t* __restrict__ B,
                                                      float* __restrict__ C,
                                                      const float* __restrict__ bias,
                                                      const unsigned* __restrict__ scal,
                                                      int slotA, int slotB,
                                                      int M, int N, int K) {
  __shared__ uint32_t As[64][17];
  __shared__ uint32_t Bs[64][17];
  int bm = blockIdx.y * 64, bn = blockIdx.x * 64;
  int t = threadIdx.x;
  float sAB = qscale(scal, slotA) * qscale(scal, slotB);
  int tx = t & 15, ty = t >> 4;
  int acc[4][4] = {};
  for (int kc = 0; kc < K; kc += 64) {
#pragma unroll
    for (int i = 0; i < 4; ++i) {
      int idx = t + 256 * i;
      int r = idx >> 4, c = idx & 15;
      As[r][c] = *(const uint32_t*)(A + (size_t)(bm + r) * K + kc + 4 * c);
      Bs[r][c] = *(const uint32_t*)(B + (size_t)(bn + r) * K + kc + 4 * c);
    }
    __syncthreads();
#pragma unroll
    for (int kk = 0; kk < 16; ++kk) {
      uint32_t a4[4], b4[4];
#pragma unroll
      for (int i = 0; i < 4; ++i) a4[i] = As[ty * 4 + i][kk];
#pragma unroll
      for (int j = 0; j < 4; ++j) b4[j] = Bs[tx * 4 + j][kk];
#pragma unroll
      for (int i = 0; i < 4; ++i)
#pragma unroll
        for (int j = 0; j < 4; ++j) acc[i][j] = dot4i8(a4[i], b4[j], acc[i][j]);
    }
    __syncthreads();
  }
#pragma unroll
  for (int i = 0; i < 4; ++i)
#pragma unroll
    for (int j = 0; j < 4; ++j) {
      int r = bm + ty * 4 + i, c = bn + tx * 4 + j;
      float v = (float)acc[i][j] * sAB;
      C[(size_t)r * N + c] = v + bias[c];
    }
}

// ---------------- attention pass 1: rowmax, rowsum, global Q1.15 max ----------------

__device__ __forceinline__ float pla_exp(float xc, const PLA& pla) {
  float mm = pla.m[0], cc = pla.c[0];
#pragma unroll
  for (int ii = 1; ii <= 10; ++ii) {   // idx clamped to <=10 (reference quirk)
    bool ge = xc >= pla.a[ii];
    mm = ge ? pla.m[ii] : mm;
    cc = ge ? pla.c[ii] : cc;
  }
  float e = mm * xc;   // no fma: contract off
  e = e + cc;
  return e;
}

__device__ __forceinline__ float fx_q3226(float x) {
  float sh = rintf(x * 67108864.0f);
  sh = fminf(fmaxf(sh, -2147483648.0f), 2147483648.0f);  // f32(2^31-1) == 2^31
  return sh * (1.0f / 67108864.0f);
}

__global__ __launch_bounds__(256) void attn_pass1(const int8_t* __restrict__ qq,
                                                  const int8_t* __restrict__ qk,
                                                  float* __restrict__ rowmax,
                                                  float* __restrict__ rowsum,
                                                  unsigned* __restrict__ scal, PLA pla) {
  __shared__ uint32_t Qs[16][17];
  __shared__ uint32_t Ks[64][17];
  __shared__ float Sc[16][512];
  int t = threadIdx.x;
  int blk = blockIdx.x;
  int rb = blk & 31;       // 512/16 row-blocks
  int bh = blk >> 5;       // 0..95
  const uint32_t* qrow = (const uint32_t*)(qq + (size_t)bh * 32768 + (size_t)rb * 1024);
  const uint32_t* krow = (const uint32_t*)(qk + (size_t)bh * 32768);
  float sq = qscale(scal, S_YQ);
  float sk = qscale(scal, S_YK);
  float pref = (sq * sk) * 0.125f;
  { int r = t >> 4, c = t & 15; Qs[r][c] = qrow[r * 16 + c]; }
  for (int kc = 0; kc < 512; kc += 64) {
#pragma unroll
    for (int i = 0; i < 4; ++i) {
      int idx = t + 256 * i;
      int r = idx >> 4, c = idx & 15;
      Ks[r][c] = krow[(kc + r) * 16 + c];
    }
    __syncthreads();
    int c0 = t & 63, rg = t >> 6;
#pragma unroll
    for (int i = 0; i < 4; ++i) {
      int r = rg * 4 + i;
      int acc = 0;
#pragma unroll
      for (int kk = 0; kk < 16; ++kk) acc = dot4i8(Qs[r][kk], Ks[c0][kk], acc);
      Sc[r][kc + c0] = (float)acc * pref;
    }
    __syncthreads();
  }
  int row = t >> 4, l16 = t & 15;
  float mx = -3.4e38f;
  for (int j = l16; j < 512; j += 16) mx = fmaxf(mx, Sc[row][j]);
  for (int off = 8; off > 0; off >>= 1) mx = fmaxf(mx, __shfl_xor(mx, off, 64));
  int sgl = bh * 512 + rb * 16 + row;
  if (l16 == 0) rowmax[sgl] = mx;
  float sum = 0.0f;
  for (int j = l16; j < 512; j += 16) {
    float x = Sc[row][j] - mx;
    float xc = fminf(fmaxf(fx_q3226(x), -10.0f), 0.0f);
    float e = pla_exp(xc, pla);
    Sc[row][j] = e;
    sum += e;
  }
  for (int off = 8; off > 0; off >>= 1) sum += __shfl_xor(sum, off, 64);
  if (l16 == 0) rowsum[sgl] = sum;
  float denom = sum + 1e-9f;
  int qmax = 0;
  for (int j = l16; j < 512; j += 16) {
    float sm = Sc[row][j] / denom;
    float q15 = rintf(sm * 32768.0f);
    q15 = fminf(fmaxf(q15, -32768.0f), 32767.0f);
    int qi = (int)q15;
    qmax = max(qmax, qi < 0 ? -qi : qi);
  }
  for (int off = 32; off > 0; off >>= 1) qmax = max(qmax, __shfl_xor(qmax, off, 64));
  if ((t & 63) == 0) atomicMax((int*)(scal + S_PMAX), qmax);
}

// ---------------- attention pass 2: recompute scores, quantize probs, PV ----------------

__global__ __launch_bounds__(256) void attn_pass2(const int8_t* __restrict__ qq,
                                                  const int8_t* __restrict__ qk,
                                                  const int8_t* __restrict__ qv,
                                                  const float* __restrict__ rowmax,
                                                  const float* __restrict__ rowsum,
                                                  unsigned* __restrict__ scal,
                                                  float* __restrict__ ctx, PLA pla) {
  __shared__ uint32_t Qs[16][17];
  __shared__ uint32_t Ks[64][17];
  __shared__ int8_t Vs[64][64];
  __shared__ int8_t Ps[16][512];
  __shared__ float rmx[16], rsm[16];
  int t = threadIdx.x;
  int blk = blockIdx.x;
  int rb = blk & 31;
  int bh = blk >> 5;
  int b = bh / 12, h = bh % 12;
  float sq = qscale(scal, S_YQ);
  float sk = qscale(scal, S_YK);
  float sv = qscale(scal, S_YV);
  float pref = (sq * sk) * 0.125f;
  int pmax = *(const int*)(scal + S_PMAX);
  float sp = fmaxf(((float)pmax * (1.0f / 32768.0f)) / QMAXF, 1e-8f);
  const uint32_t* qrow = (const uint32_t*)(qq + (size_t)bh * 32768 + (size_t)rb * 1024);
  const uint32_t* krow = (const uint32_t*)(qk + (size_t)bh * 32768);
  const uint32_t* vrow = (const uint32_t*)(qv + (size_t)bh * 32768);
  { int r = t >> 4, c = t & 15; Qs[r][c] = qrow[r * 16 + c]; }
  if (t < 16) {
    int sg = bh * 512 + rb * 16 + t;
    rmx[t] = rowmax[sg];
    rsm[t] = rowsum[sg] + 1e-9f;
  }
  for (int kc = 0; kc < 512; kc += 64) {
#pragma unroll
    for (int i = 0; i < 4; ++i) {
      int idx = t + 256 * i;
      int r = idx >> 4, c = idx & 15;
      Ks[r][c] = krow[(kc + r) * 16 + c];
    }
    __syncthreads();
    int c0 = t & 63, rg = t >> 6;
#pragma unroll
    for (int i = 0; i < 4; ++i) {
      int r = rg * 4 + i;
      int acc = 0;
#pragma unroll
      for (int kk = 0; kk < 16; ++kk) acc = dot4i8(Qs[r][kk], Ks[c0][kk], acc);
      float v = (float)acc * pref;
      float x = v - rmx[r];
      float xc = fminf(fmaxf(fx_q3226(x), -10.0f), 0.0f);
      float e = pla_exp(xc, pla);
      float sm = e / rsm[r];
      float q15 = rintf(sm * 32768.0f);
      q15 = fminf(fmaxf(q15, -32768.0f), 32767.0f);
      float pv = q15 * (1.0f / 32768.0f);
      float qp = fminf(fmaxf(rintf(pv / sp), -127.0f), 127.0f);
      Ps[r][kc + c0] = (int8_t)qp;
    }
    __syncthreads();
  }
  // PV: ctx[r][d] = sum_k Ps[r][k] * V[k][d]
  int d = t & 63;
  int rg4 = (t >> 6) * 4;
  int racc[4] = {0, 0, 0, 0};
  for (int kc = 0; kc < 512; kc += 64) {
#pragma unroll
    for (int i = 0; i < 4; ++i) {
      int idx = t + 256 * i;
      int r = idx >> 4, c = idx & 15;
      *(uint32_t*)&Vs[r][c * 4] = vrow[(kc + r) * 16 + c];
    }
    __syncthreads();
    for (int kk = 0; kk < 64; ++kk) {
      int vb = (int)Vs[kk][d];
#pragma unroll
      for (int i = 0; i < 4; ++i) racc[i] += (int)Ps[rg4 + i][kc + kk] * vb;
    }
    __syncthreads();
  }
  float spv = sp * sv;
  float am = 0.0f;
#pragma unroll
  for (int i = 0; i < 4; ++i) {
    int r = rg4 + i;
    int sgl = rb * 16 + r;
    float val = (float)racc[i] * spv;
    ctx[((size_t)(b * 512 + sgl)) * 768 + h * 64 + d] = val;
    am = fmaxf(am, fabsf(val));
  }
  for (int off = 32; off > 0; off >>= 1) am = fmaxf(am, __shfl_xor(am, off, 64));
  if ((t & 63) == 0) atomicMax(scal + S_CTX, __float_as_uint(am));
}

// ---------------- ctx double-quant ----------------

__global__ __launch_bounds__(256) void ctx_q1_kernel(const float* __restrict__ ctx,
                                                     int8_t* __restrict__ i1,
                                                     unsigned* __restrict__ scal) {
  int i = blockIdx.x * 256 + threadIdx.x;  // n exact multiple of 256
  float s1 = qscale(scal, S_CTX);
  float t = fminf(fmaxf(rintf(ctx[i] / s1), -127.0f), 127.0f);
  i1[i] = (int8_t)t;
  float y = fabsf(t * s1);
  for (int off = 32; off > 0; off >>= 1) y = fmaxf(y, __shfl_xor(y, off, 64));
  __shared__ float red[4];
  int lane = threadIdx.x & 63, w = threadIdx.x >> 6;
  if (lane == 0) red[w] = y;
  __syncthreads();
  if (threadIdx.x == 0) {
    float mm = fmaxf(fmaxf(red[0], red[1]), fmaxf(red[2], red[3]));
    atomicMax(scal + S_CTXQ1, __float_as_uint(mm));
  }
}

__global__ __launch_bounds__(256) void ctx_q2_kernel(const int8_t* __restrict__ i1,
                                                     int8_t* __restrict__ q2,
                                                     const unsigned* __restrict__ scal) {
  int i = blockIdx.x * 256 + threadIdx.x;
  float s1 = qscale(scal, S_CTX);
  float s2 = qscale(scal, S_CTXQ1);
  float y = (float)i1[i] * s1;
  q2[i] = (int8_t)fminf(fmaxf(rintf(y / s2), -127.0f), 127.0f);
}

// ---------------- host: PLA build (replicates np.polyfit degree-1 LS in f64) ----------------

static void build_pla(PLA& p) {
  double xs[1001], ys[1001];
  double step = 10.0 / 1000.0;
  for (int j = 0; j <= 1000; ++j) xs[j] = (double)j * step + (-10.0);
  xs[1000] = 0.0;
  for (int j = 0; j <= 1000; ++j) ys[j] = exp(xs[j]);
  double estep = 10.0 / 12.0;
  for (int i = 0; i < 12; ++i) {
    double a = (double)i * estep + (-10.0);
    double bb = (i + 1 == 12) ? 0.0 : (double)(i + 1) * estep + (-10.0);
    double n = 0, Sx = 0, Sy = 0, Sxx = 0, Sxy = 0;
    for (int j = 0; j <= 1000; ++j) {
      if (xs[j] >= a && xs[j] <= bb) {
        double x = xs[j], y = ys[j];
        n += 1.0; Sx += x; Sy += y; Sxx += x * x; Sxy += x * y;
      }
    }
    double det = n * Sxx - Sx * Sx;
    p.m[i] = (float)((n * Sxy - Sx * Sy) / det);
    p.c[i] = (float)((Sxx * Sy - Sx * Sxy) / det);
    p.a[i] = (float)a;
  }
}

// ---------------- launch ----------------

extern "C" void kernel_launch(void* const* d_in, const int* in_sizes, int n_in,
                              void* d_out, int out_size, void* d_ws, size_t ws_size,
                              hipStream_t stream) {
  const float* X  = (const float*)d_in[0];
  const float* Wq = (const float*)d_in[1];
  const float* bq = (const float*)d_in[2];
  const float* Wk = (const float*)d_in[3];
  const float* bk = (const float*)d_in[4];
  const float* Wv = (const float*)d_in[5];
  const float* bv = (const float*)d_in[6];
  const float* Wo = (const float*)d_in[7];
  const float* bo = (const float*)d_in[8];
  float* out = (float*)d_out;

  PLA pla;
  build_pla(pla);

  const int NX = 8 * 512 * 768;  // 3145728
  const int NW = 768 * 768;      // 589824
  const int NB = 768;

  uint8_t* ws = (uint8_t*)d_ws;
  size_t off = 0;
  auto alloc = [&](size_t bytes) -> void* {
    void* p = ws + off;
    off += (bytes + 255) & ~(size_t)255;
    return p;
  };
  unsigned* scal = (unsigned*)alloc(64 * 4);
  int8_t* qX  = (int8_t*)alloc(NX);
  int8_t* qWq = (int8_t*)alloc(NW);
  int8_t* qWk = (int8_t*)alloc(NW);
  int8_t* qWv = (int8_t*)alloc(NW);
  int8_t* qWo = (int8_t*)alloc(NW);
  float* qbq = (float*)alloc(NB * 4);
  float* qbk = (float*)alloc(NB * 4);
  float* qbv = (float*)alloc(NB * 4);
  float* qbo = (float*)alloc(NB * 4);
  float* Y   = (float*)alloc((size_t)NX * 4);   // reused as ctx
  int8_t* qq = (int8_t*)alloc(NX);
  int8_t* qk = (int8_t*)alloc(NX);
  int8_t* qv = (int8_t*)alloc(NX);
  float* rowmax = (float*)alloc(96 * 512 * 4);
  float* rowsum = (float*)alloc(96 * 512 * 4);
  int8_t* i1    = qX;  // reuse: qX dead after QKV GEMMs
  int8_t* qctx2 = qq;  // reuse: qq dead after attention pass 2
  float* ctx    = Y;   // reuse: Y dead after quant_heads(v)
  (void)ws_size; (void)n_in; (void)in_sizes; (void)out_size;

  zero_scal_kernel<<<1, 64, 0, stream>>>(scal);

  maxabs_kernel<<<2048, 256, 0, stream>>>(X, NX, scal + S_X);
  maxabs_kernel<<<1024, 256, 0, stream>>>(Wq, NW, scal + S_WQ);
  maxabs_kernel<<<1024, 256, 0, stream>>>(Wk, NW, scal + S_WK);
  maxabs_kernel<<<1024, 256, 0, stream>>>(Wv, NW, scal + S_WV);
  maxabs_kernel<<<1024, 256, 0, stream>>>(Wo, NW, scal + S_WO);
  maxabs_kernel<<<3, 256, 0, stream>>>(bq, NB, scal + S_BQ);
  maxabs_kernel<<<3, 256, 0, stream>>>(bk, NB, scal + S_BK);
  maxabs_kernel<<<3, 256, 0, stream>>>(bv, NB, scal + S_BV);
  maxabs_kernel<<<3, 256, 0, stream>>>(bo, NB, scal + S_BO);

  quant_kernel<<<NX / 256, 256, 0, stream>>>(X, qX, NX, scal, S_X);
  quant_kernel<<<NW / 256, 256, 0, stream>>>(Wq, qWq, NW, scal, S_WQ);
  quant_kernel<<<NW / 256, 256, 0, stream>>>(Wk, qWk, NW, scal, S_WK);
  quant_kernel<<<NW / 256, 256, 0, stream>>>(Wv, qWv, NW, scal, S_WV);
  quant_kernel<<<NW / 256, 256, 0, stream>>>(Wo, qWo, NW, scal, S_WO);

  qbias_kernel<<<3, 256, 0, stream>>>(bq, qbq, scal, S_X, S_WQ, S_BQ);
  qbias_kernel<<<3, 256, 0, stream>>>(bk, qbk, scal, S_X, S_WK, S_BK);
  qbias_kernel<<<3, 256, 0, stream>>>(bv, qbv, scal, S_X, S_WV, S_BV);

  dim3 ggrid(12, 64);
  // Q projection
  gemm_i8_kernel<<<ggrid, 256, 0, stream>>>(qX, qWq, Y, qbq, scal, S_X, S_WQ, 4096, 768, 768);
  maxabs_kernel<<<2048, 256, 0, stream>>>(Y, NX, scal + S_YQ);
  quant_heads_kernel<<<NX / 256, 256, 0, stream>>>(Y, qq, scal, S_YQ);
  // K projection
  gemm_i8_kernel<<<ggrid, 256, 0, stream>>>(qX, qWk, Y, qbk, scal, S_X, S_WK, 4096, 768, 768);
  maxabs_kernel<<<2048, 256, 0, stream>>>(Y, NX, scal + S_YK);
  quant_heads_kernel<<<NX / 256, 256, 0, stream>>>(Y, qk, scal, S_YK);
  // V projection
  gemm_i8_kernel<<<ggrid, 256, 0, stream>>>(qX, qWv, Y, qbv, scal, S_X, S_WV, 4096, 768, 768);
  maxabs_kernel<<<2048, 256, 0, stream>>>(Y, NX, scal + S_YV);
  quant_heads_kernel<<<NX / 256, 256, 0, stream>>>(Y, qv, scal, S_YV);

  attn_pass1<<<3072, 256, 0, stream>>>(qq, qk, rowmax, rowsum, scal, pla);
  attn_pass2<<<3072, 256, 0, stream>>>(qq, qk, qv, rowmax, rowsum, scal, ctx, pla);

  ctx_q1_kernel<<<NX / 256, 256, 0, stream>>>(ctx, i1, scal);
  qbias_kernel<<<3, 256, 0, stream>>>(bo, qbo, scal, S_CTXQ1, S_WO, S_BO);
  ctx_q2_kernel<<<NX / 256, 256, 0, stream>>>(i1, qctx2, scal);
  gemm_i8_kernel<<<ggrid, 256, 0, stream>>>(qctx2, qWo, out, qbo, scal, S_CTXQ1, S_WO, 4096, 768, 768);
}

// Round 2
// 447.306 us; speedup vs baseline: 2.6813x; 2.6813x over previous
//
#include <hip/hip_runtime.h>
#include <cstdint>
#include <cmath>
#include <cstddef>

#pragma clang fp contract(off)

#define QMAXF 127.0f

typedef int i32x4 __attribute__((ext_vector_type(4)));

enum {
  S_X = 0, S_WQ, S_WK, S_WV, S_WO, S_BQ, S_BK, S_BV, S_BO,
  S_YQ, S_YK, S_YV, S_PMAX, S_CTX, S_CTXQ1, S_COUNT
};

struct PLA { float m[12]; float c[12]; float a[12]; };

// ---------------- device helpers ----------------

__device__ __forceinline__ float qscale(const unsigned* scal, int slot) {
  // reference: scale = max(maxabs / 127.0, 1e-8)
  return fmaxf(__uint_as_float(scal[slot]) / QMAXF, 1e-8f);
}

__device__ __forceinline__ void block_atomic_maxf(float v, unsigned* slot) {
  for (int off = 32; off > 0; off >>= 1) v = fmaxf(v, __shfl_xor(v, off, 64));
  __shared__ float red[4];
  int lane = threadIdx.x & 63, w = threadIdx.x >> 6;
  if (lane == 0) red[w] = v;
  __syncthreads();
  if (threadIdx.x == 0)
    atomicMax(slot, __float_as_uint(fmaxf(fmaxf(red[0], red[1]), fmaxf(red[2], red[3]))));
}

__device__ __forceinline__ int qpack4(float a0, float a1, float a2, float a3, float s) {
  int i0 = (int)fminf(fmaxf(rintf(a0 / s), -QMAXF), QMAXF);
  int i1 = (int)fminf(fmaxf(rintf(a1 / s), -QMAXF), QMAXF);
  int i2 = (int)fminf(fmaxf(rintf(a2 / s), -QMAXF), QMAXF);
  int i3 = (int)fminf(fmaxf(rintf(a3 / s), -QMAXF), QMAXF);
  return (i0 & 255) | ((i1 & 255) << 8) | ((i2 & 255) << 16) | ((i3 & 255) << 24);
}

__device__ __forceinline__ float pla_exp(float xc, const PLA& pla) {
  float mm = pla.m[0], cc = pla.c[0];
#pragma unroll
  for (int ii = 1; ii <= 10; ++ii) {   // idx clamped to <=10 (reference quirk)
    bool ge = xc >= pla.a[ii];
    mm = ge ? pla.m[ii] : mm;
    cc = ge ? pla.c[ii] : cc;
  }
  float e = mm * xc;   // no fma: contract off
  e = e + cc;
  return e;
}

__device__ __forceinline__ float fx_q3226(float x) {
  float sh = rintf(x * 67108864.0f);
  sh = fminf(fmaxf(sh, -2147483648.0f), 2147483648.0f);  // f32(2^31-1) == 2^31
  return sh * (1.0f / 67108864.0f);
}

// ---------------- tiny kernels ----------------

__global__ void zero_scal_kernel(unsigned* s) {
  if (threadIdx.x < 16) s[threadIdx.x] = 0u;
}

__global__ __launch_bounds__(256) void maxabs4_kernel(const float4* __restrict__ x, int n4,
                                                      unsigned* __restrict__ slot) {
  float m = 0.0f;
  for (int i = blockIdx.x * 256 + threadIdx.x; i < n4; i += gridDim.x * 256) {
    float4 v = x[i];
    m = fmaxf(m, fmaxf(fmaxf(fabsf(v.x), fabsf(v.y)), fmaxf(fabsf(v.z), fabsf(v.w))));
  }
  block_atomic_maxf(m, slot);
}

// 4 weights in one launch: grid (576, 4), 576*256 == 768*768/4
__global__ __launch_bounds__(256) void maxabs_w4_kernel(const float4* __restrict__ w0, const float4* __restrict__ w1,
                                                        const float4* __restrict__ w2, const float4* __restrict__ w3,
                                                        unsigned* __restrict__ scal) {
  const float4* p = (blockIdx.y == 0) ? w0 : (blockIdx.y == 1) ? w1 : (blockIdx.y == 2) ? w2 : w3;
  int i = blockIdx.x * 256 + threadIdx.x;
  float4 v = p[i];
  float m = fmaxf(fmaxf(fabsf(v.x), fabsf(v.y)), fmaxf(fabsf(v.z), fabsf(v.w)));
  block_atomic_maxf(m, scal + S_WQ + blockIdx.y);
}

// 4 biases in one launch: grid 4 blocks
__global__ __launch_bounds__(256) void maxabs_bias_kernel(const float* __restrict__ b0, const float* __restrict__ b1,
                                                          const float* __restrict__ b2, const float* __restrict__ b3,
                                                          unsigned* __restrict__ scal) {
  const float* p = (blockIdx.x == 0) ? b0 : (blockIdx.x == 1) ? b1 : (blockIdx.x == 2) ? b2 : b3;
  float m = 0.0f;
  for (int i = threadIdx.x; i < 768; i += 256) m = fmaxf(m, fabsf(p[i]));
  block_atomic_maxf(m, scal + S_BQ + blockIdx.x);
}

__global__ __launch_bounds__(256) void quant4_kernel(const float4* __restrict__ x, int* __restrict__ q,
                                                     const unsigned* __restrict__ scal, int slot) {
  int i = blockIdx.x * 256 + threadIdx.x;   // exact grid
  float s = qscale(scal, slot);
  float4 v = x[i];
  q[i] = qpack4(v.x, v.y, v.z, v.w, s);
}

// 4 weights quant in one launch: grid (576, 4)
__global__ __launch_bounds__(256) void quant4_w_kernel(const float4* __restrict__ w0, const float4* __restrict__ w1,
                                                       const float4* __restrict__ w2, const float4* __restrict__ w3,
                                                       int* __restrict__ o0, int* __restrict__ o1,
                                                       int* __restrict__ o2, int* __restrict__ o3,
                                                       const unsigned* __restrict__ scal) {
  int which = blockIdx.y;
  const float4* p = (which == 0) ? w0 : (which == 1) ? w1 : (which == 2) ? w2 : w3;
  int* o = (which == 0) ? o0 : (which == 1) ? o1 : (which == 2) ? o2 : o3;
  int i = blockIdx.x * 256 + threadIdx.x;
  float s = qscale(scal, S_WQ + which);
  float4 v = p[i];
  o[i] = qpack4(v.x, v.y, v.z, v.w, s);
}

__global__ void qbias_kernel(const float* __restrict__ b, float* __restrict__ qb,
                             const unsigned* __restrict__ scal, int slotX, int slotW, int slotB) {
  int j = blockIdx.x * 256 + threadIdx.x;
  if (j >= 768) return;
  float in_scale = __uint_as_float(scal[slotX]) / QMAXF;   // no clamp (reference)
  float w_scale  = __uint_as_float(scal[slotW]) / QMAXF;
  float bias_scale = in_scale * w_scale;
  float tmax = __uint_as_float(scal[slotB]) / bias_scale;
  float st = fmaxf(tmax / QMAXF, 1e-8f);
  float t = b[j] / bias_scale;
  float qv = fminf(fmaxf(rintf(t / st), -127.0f), 127.0f) * st;
  qb[j] = qv * bias_scale;
}

// Y [B*S][768] -> int8 head layout [(b*12+h)][512][64], packed int writes
__global__ __launch_bounds__(256) void quant_heads_qk_kernel(const float* __restrict__ Y, int* __restrict__ q,
                                                             const unsigned* __restrict__ scal, int slot) {
  int i = blockIdx.x * 256 + threadIdx.x;  // over 786432 int4-groups, grid 3072
  float s = qscale(scal, slot);
  int d0 = (i & 15) * 4;
  int sI = (i >> 4) & 511;
  int bh = i >> 13;
  int h = bh % 12, b = bh / 12;
  const float* src = Y + ((size_t)(b * 512 + sI)) * 768 + h * 64 + d0;
  float4 v = *(const float4*)src;
  q[i] = qpack4(v.x, v.y, v.z, v.w, s);   // dest byte offset == 4*i == bh*32768 + sI*64 + d0
}

// V: quantize + transpose into [bh][64 d][512 s]
__global__ __launch_bounds__(256) void quant_heads_v_kernel(const float* __restrict__ Y, int8_t* __restrict__ q,
                                                            const unsigned* __restrict__ scal) {
  __shared__ int8_t T[64][68];
  int bh = blockIdx.x >> 3, sb = blockIdx.x & 7;   // grid 96*8
  int b = bh / 12, h = bh % 12;
  float s = qscale(scal, S_YV);
  int d = threadIdx.x & 63, sl = threadIdx.x >> 6;
#pragma unroll
  for (int i = 0; i < 16; ++i) {
    int s_local = i * 4 + sl;
    float y = Y[((size_t)(b * 512 + sb * 64 + s_local)) * 768 + h * 64 + d];
    float tq = fminf(fmaxf(rintf(y / s), -QMAXF), QMAXF);
    T[d][s_local] = (int8_t)tq;
  }
  __syncthreads();
  int s4 = (threadIdx.x & 15) * 4, dl = threadIdx.x >> 4;
#pragma unroll
  for (int i = 0; i < 4; ++i) {
    int d_ = i * 16 + dl;
    int packed = (T[d_][s4] & 255) | ((T[d_][s4 + 1] & 255) << 8) |
                 ((T[d_][s4 + 2] & 255) << 16) | ((T[d_][s4 + 3] & 255) << 24);
    *(int*)(q + (size_t)bh * 32768 + (size_t)d_ * 512 + sb * 64 + s4) = packed;
  }
}

// ---------------- MFMA int8 GEMM:  C[4096][768] = A[4096][768] . B[768][768]^T * sA*sB + bias ----------------

__global__ __launch_bounds__(256) void gemm_i8_mfma(const int8_t* __restrict__ A, const int8_t* __restrict__ Bm,
                                                    float* __restrict__ C, const float* __restrict__ bias,
                                                    unsigned* __restrict__ scal, int slotA, int slotB, int maxslot) {
  int t = threadIdx.x, lane = t & 63, w = t >> 6, l15 = lane & 15, kg = lane >> 4;
  int bm = blockIdx.y * 64, bn = blockIdx.x * 64;
  float sAB = qscale(scal, slotA) * qscale(scal, slotB);
  const int8_t* ap = A + (size_t)(bm + w * 16 + l15) * 768 + kg * 16;
  const int8_t* bp = Bm + (size_t)(bn + l15) * 768 + kg * 16;
  i32x4 acc[4] = {{0,0,0,0}, {0,0,0,0}, {0,0,0,0}, {0,0,0,0}};
#pragma unroll
  for (int kc = 0; kc < 768; kc += 64) {
    i32x4 af = *(const i32x4*)(ap + kc);
#pragma unroll
    for (int ct = 0; ct < 4; ++ct) {
      i32x4 bf = *(const i32x4*)(bp + (size_t)ct * 16 * 768 + kc);
      acc[ct] = __builtin_amdgcn_mfma_i32_16x16x64_i8(af, bf, acc[ct], 0, 0, 0);
    }
  }
  float am = 0.0f;
#pragma unroll
  for (int ct = 0; ct < 4; ++ct) {
    float bv = bias[bn + ct * 16 + l15];
#pragma unroll
    for (int r = 0; r < 4; ++r) {
      int row = bm + w * 16 + kg * 4 + r;                 // C/D: col=lane&15, row=(lane>>4)*4+reg
      float v = (float)acc[ct][r] * sAB;
      float yv = v + bv;
      C[(size_t)row * 768 + bn + ct * 16 + l15] = yv;
      am = fmaxf(am, fabsf(yv));
    }
  }
  if (maxslot >= 0) block_atomic_maxf(am, scal + maxslot);
}

// ---------------- attention (per 16 q-rows x full 512 cols; shared code => bit-identical passes) ----------------

__device__ __forceinline__ void attn_scores_to_lds(const int8_t* __restrict__ qbase,
                                                   const int8_t* __restrict__ kbase,
                                                   float (*Sc)[520], int rb, float pref) {
  int t = threadIdx.x, lane = t & 63, w = t >> 6, l15 = lane & 15, kg = lane >> 4;
  i32x4 zero = {0, 0, 0, 0};
  i32x4 qf = *(const i32x4*)(qbase + (size_t)(rb * 16 + l15) * 64 + kg * 16);
#pragma unroll
  for (int i = 0; i < 8; ++i) {
    int ct = w * 8 + i;
    i32x4 kf = *(const i32x4*)(kbase + (size_t)(ct * 16 + l15) * 64 + kg * 16);
    i32x4 acc = __builtin_amdgcn_mfma_i32_16x16x64_i8(qf, kf, zero, 0, 0, 0);
#pragma unroll
    for (int r = 0; r < 4; ++r)
      Sc[kg * 4 + r][w * 128 + i * 16 + l15] = (float)acc[r] * pref;
  }
  __syncthreads();
}

__device__ __forceinline__ float softmax_e_phase(float (*Sc)[520], const PLA& pla) {
  int t = threadIdx.x, row = t >> 4, l16 = t & 15;
  float mx = -3.4e38f;
  for (int j = l16; j < 512; j += 16) mx = fmaxf(mx, Sc[row][j]);
  for (int off = 8; off > 0; off >>= 1) mx = fmaxf(mx, __shfl_xor(mx, off, 64));
  float sum = 0.0f;
  for (int j = l16; j < 512; j += 16) {
    float x = Sc[row][j] - mx;
    float xc = fminf(fmaxf(fx_q3226(x), -10.0f), 0.0f);
    float e = pla_exp(xc, pla);
    Sc[row][j] = e;
    sum += e;
  }
  for (int off = 8; off > 0; off >>= 1) sum += __shfl_xor(sum, off, 64);
  return sum + 1e-9f;
}

__global__ __launch_bounds__(256) void attn_scores_pass(const int8_t* __restrict__ qq,
                                                        const int8_t* __restrict__ qk,
                                                        unsigned* __restrict__ scal, PLA pla) {
  __shared__ float Sc[16][520];
  int rb = blockIdx.x & 31, bh = blockIdx.x >> 5;
  float pref = (qscale(scal, S_YQ) * qscale(scal, S_YK)) * 0.125f;
  attn_scores_to_lds(qq + (size_t)bh * 32768, qk + (size_t)bh * 32768, Sc, rb, pref);
  float denom = softmax_e_phase(Sc, pla);
  int t = threadIdx.x, row = t >> 4, l16 = t & 15;
  int qmax = 0;
  for (int j = l16; j < 512; j += 16) {
    float sm = Sc[row][j] / denom;
    float q15 = rintf(sm * 32768.0f);
    q15 = fminf(fmaxf(q15, -32768.0f), 32767.0f);
    int qi = (int)q15;
    qmax = max(qmax, qi < 0 ? -qi : qi);
  }
  for (int off = 32; off > 0; off >>= 1) qmax = max(qmax, __shfl_xor(qmax, off, 64));
  if ((t & 63) == 0) atomicMax((int*)(scal + S_PMAX), qmax);
}

__global__ __launch_bounds__(256) void attn_pv_pass(const int8_t* __restrict__ qq,
                                                    const int8_t* __restrict__ qk,
                                                    const int8_t* __restrict__ vT,
                                                    unsigned* __restrict__ scal,
                                                    float* __restrict__ ctx, PLA pla) {
  __shared__ float Sc[16][520];
  __shared__ alignas(16) int8_t Ps[16][528];
  int rb = blockIdx.x & 31, bh = blockIdx.x >> 5;
  int b = bh / 12, h = bh % 12;
  float sq = qscale(scal, S_YQ), sk = qscale(scal, S_YK), sv = qscale(scal, S_YV);
  float pref = (sq * sk) * 0.125f;
  int pmax = *(const int*)(scal + S_PMAX);
  float sp = fmaxf(((float)pmax * (1.0f / 32768.0f)) / QMAXF, 1e-8f);
  attn_scores_to_lds(qq + (size_t)bh * 32768, qk + (size_t)bh * 32768, Sc, rb, pref);
  float denom = softmax_e_phase(Sc, pla);
  int t = threadIdx.x, row = t >> 4, l16 = t & 15;
  for (int j = l16; j < 512; j += 16) {
    float sm = Sc[row][j] / denom;
    float q15 = rintf(sm * 32768.0f);
    q15 = fminf(fmaxf(q15, -32768.0f), 32767.0f);
    float pv = q15 * (1.0f / 32768.0f);
    float qp = fminf(fmaxf(rintf(pv / sp), -QMAXF), QMAXF);
    Ps[row][j] = (int8_t)qp;
  }
  __syncthreads();
  int lane = t & 63, w = t >> 6, l15 = lane & 15, kg = lane >> 4;
  i32x4 pacc = {0, 0, 0, 0};
  const int8_t* vbase = vT + (size_t)bh * 32768 + (size_t)(w * 16 + l15) * 512;
#pragma unroll
  for (int ks = 0; ks < 8; ++ks) {
    i32x4 pf = *(const i32x4*)&Ps[l15][ks * 64 + kg * 16];
    i32x4 vf = *(const i32x4*)(vbase + ks * 64 + kg * 16);
    pacc = __builtin_amdgcn_mfma_i32_16x16x64_i8(pf, vf, pacc, 0, 0, 0);
  }
  float spv = sp * sv;
  float am = 0.0f;
#pragma unroll
  for (int r = 0; r < 4; ++r) {
    int srow = rb * 16 + kg * 4 + r;
    float val = (float)pacc[r] * spv;
    ctx[((size_t)(b * 512 + srow)) * 768 + h * 64 + w * 16 + l15] = val;
    am = fmaxf(am, fabsf(val));
  }
  block_atomic_maxf(am, scal + S_CTX);
}

// ---------------- ctx double-quant (vectorized) ----------------

__global__ __launch_bounds__(256) void ctx_q1_kernel(const float4* __restrict__ ctx, int* __restrict__ i1,
                                                     unsigned* __restrict__ scal) {
  int i = blockIdx.x * 256 + threadIdx.x;   // exact grid 3072
  float s1 = qscale(scal, S_CTX);
  float4 c = ctx[i];
  int q0 = (int)fminf(fmaxf(rintf(c.x / s1), -QMAXF), QMAXF);
  int q1 = (int)fminf(fmaxf(rintf(c.y / s1), -QMAXF), QMAXF);
  int q2 = (int)fminf(fmaxf(rintf(c.z / s1), -QMAXF), QMAXF);
  int q3 = (int)fminf(fmaxf(rintf(c.w / s1), -QMAXF), QMAXF);
  i1[i] = (q0 & 255) | ((q1 & 255) << 8) | ((q2 & 255) << 16) | ((q3 & 255) << 24);
  float am = fmaxf(fmaxf(fabsf((float)q0 * s1), fabsf((float)q1 * s1)),
                   fmaxf(fabsf((float)q2 * s1), fabsf((float)q3 * s1)));
  block_atomic_maxf(am, scal + S_CTXQ1);
}

__global__ __launch_bounds__(256) void ctx_q2_kernel(const int* __restrict__ i1, int* __restrict__ q2o,
                                                     const unsigned* __restrict__ scal) {
  int i = blockIdx.x * 256 + threadIdx.x;
  float s1 = qscale(scal, S_CTX);
  float s2 = qscale(scal, S_CTXQ1);
  int v = i1[i];
  int out = 0;
#pragma unroll
  for (int k = 0; k < 4; ++k) {
    float y = (float)((int8_t)(v >> (8 * k))) * s1;
    int qq = (int)fminf(fmaxf(rintf(y / s2), -QMAXF), QMAXF);
    out |= (qq & 255) << (8 * k);
  }
  q2o[i] = out;
}

// ---------------- host: PLA build (replicates np.polyfit degree-1 LS in f64) ----------------

static void build_pla(PLA& p) {
  double xs[1001], ys[1001];
  double step = 10.0 / 1000.0;
  for (int j = 0; j <= 1000; ++j) xs[j] = (double)j * step + (-10.0);
  xs[1000] = 0.0;
  for (int j = 0; j <= 1000; ++j) ys[j] = exp(xs[j]);
  double estep = 10.0 / 12.0;
  for (int i = 0; i < 12; ++i) {
    double a = (double)i * estep + (-10.0);
    double bb = (i + 1 == 12) ? 0.0 : (double)(i + 1) * estep + (-10.0);
    double n = 0, Sx = 0, Sy = 0, Sxx = 0, Sxy = 0;
    for (int j = 0; j <= 1000; ++j) {
      if (xs[j] >= a && xs[j] <= bb) {
        double x = xs[j], y = ys[j];
        n += 1.0; Sx += x; Sy += y; Sxx += x * x; Sxy += x * y;
      }
    }
    double det = n * Sxx - Sx * Sx;
    p.m[i] = (float)((n * Sxy - Sx * Sy) / det);
    p.c[i] = (float)((Sxx * Sy - Sx * Sxy) / det);
    p.a[i] = (float)a;
  }
}

// ---------------- launch ----------------

extern "C" void kernel_launch(void* const* d_in, const int* in_sizes, int n_in,
                              void* d_out, int out_size, void* d_ws, size_t ws_size,
                              hipStream_t stream) {
  const float* X  = (const float*)d_in[0];
  const float* Wq = (const float*)d_in[1];
  const float* bq = (const float*)d_in[2];
  const float* Wk = (const float*)d_in[3];
  const float* bk = (const float*)d_in[4];
  const float* Wv = (const float*)d_in[5];
  const float* bv = (const float*)d_in[6];
  const float* Wo = (const float*)d_in[7];
  const float* bo = (const float*)d_in[8];
  float* out = (float*)d_out;

  PLA pla;
  build_pla(pla);

  const int NX = 8 * 512 * 768;  // 3145728
  const int NW = 768 * 768;      // 589824
  const int NB = 768;

  uint8_t* ws = (uint8_t*)d_ws;
  size_t off = 0;
  auto alloc = [&](size_t bytes) -> void* {
    void* p = ws + off;
    off += (bytes + 255) & ~(size_t)255;
    return p;
  };
  unsigned* scal = (unsigned*)alloc(64 * 4);
  int8_t* qX  = (int8_t*)alloc(NX);
  int8_t* qWq = (int8_t*)alloc(NW);
  int8_t* qWk = (int8_t*)alloc(NW);
  int8_t* qWv = (int8_t*)alloc(NW);
  int8_t* qWo = (int8_t*)alloc(NW);
  float* qbq = (float*)alloc(NB * 4);
  float* qbk = (float*)alloc(NB * 4);
  float* qbv = (float*)alloc(NB * 4);
  float* qbo = (float*)alloc(NB * 4);
  float* Y   = (float*)alloc((size_t)NX * 4);   // reused as ctx
  int8_t* qq = (int8_t*)alloc(NX);
  int8_t* qk = (int8_t*)alloc(NX);
  int8_t* qvT = (int8_t*)alloc(NX);
  int8_t* i1    = qX;  // reuse: qX dead after QKV GEMMs
  int8_t* qctx2 = qq;  // reuse: qq dead after attention PV pass
  float* ctx    = Y;   // reuse: Y dead after quant_heads_v
  (void)ws_size; (void)n_in; (void)in_sizes; (void)out_size;

  zero_scal_kernel<<<1, 64, 0, stream>>>(scal);

  maxabs4_kernel<<<1024, 256, 0, stream>>>((const float4*)X, NX / 4, scal + S_X);
  maxabs_w4_kernel<<<dim3(576, 4), 256, 0, stream>>>((const float4*)Wq, (const float4*)Wk,
                                                     (const float4*)Wv, (const float4*)Wo, scal);
  maxabs_bias_kernel<<<4, 256, 0, stream>>>(bq, bk, bv, bo, scal);

  quant4_kernel<<<3072, 256, 0, stream>>>((const float4*)X, (int*)qX, scal, S_X);
  quant4_w_kernel<<<dim3(576, 4), 256, 0, stream>>>((const float4*)Wq, (const float4*)Wk,
                                                    (const float4*)Wv, (const float4*)Wo,
                                                    (int*)qWq, (int*)qWk, (int*)qWv, (int*)qWo, scal);

  qbias_kernel<<<3, 256, 0, stream>>>(bq, qbq, scal, S_X, S_WQ, S_BQ);
  qbias_kernel<<<3, 256, 0, stream>>>(bk, qbk, scal, S_X, S_WK, S_BK);
  qbias_kernel<<<3, 256, 0, stream>>>(bv, qbv, scal, S_X, S_WV, S_BV);

  dim3 ggrid(12, 64);
  gemm_i8_mfma<<<ggrid, 256, 0, stream>>>(qX, qWq, Y, qbq, scal, S_X, S_WQ, S_YQ);
  quant_heads_qk_kernel<<<3072, 256, 0, stream>>>(Y, (int*)qq, scal, S_YQ);
  gemm_i8_mfma<<<ggrid, 256, 0, stream>>>(qX, qWk, Y, qbk, scal, S_X, S_WK, S_YK);
  quant_heads_qk_kernel<<<3072, 256, 0, stream>>>(Y, (int*)qk, scal, S_YK);
  gemm_i8_mfma<<<ggrid, 256, 0, stream>>>(qX, qWv, Y, qbv, scal, S_X, S_WV, S_YV);
  quant_heads_v_kernel<<<768, 256, 0, stream>>>(Y, qvT, scal);

  attn_scores_pass<<<3072, 256, 0, stream>>>(qq, qk, scal, pla);
  attn_pv_pass<<<3072, 256, 0, stream>>>(qq, qk, qvT, scal, ctx, pla);

  ctx_q1_kernel<<<3072, 256, 0, stream>>>((const float4*)ctx, (int*)i1, scal);
  qbias_kernel<<<3, 256, 0, stream>>>(bo, qbo, scal, S_CTXQ1, S_WO, S_BO);
  ctx_q2_kernel<<<3072, 256, 0, stream>>>((const int*)i1, (int*)qctx2, scal);
  gemm_i8_mfma<<<ggrid, 256, 0, stream>>>(qctx2, qWo, out, qbo, scal, S_CTXQ1, S_WO, -1);
}

// Round 3
// 316.233 us; speedup vs baseline: 3.7926x; 1.4145x over previous
//
#include <hip/hip_runtime.h>
#include <cstdint>
#include <cmath>
#include <cstddef>

#pragma clang fp contract(off)

#define QMAXF 127.0f

typedef int i32x4 __attribute__((ext_vector_type(4)));

enum {
  S_X = 0, S_WQ, S_WK, S_WV, S_WO, S_BQ, S_BK, S_BV, S_BO,
  S_YQ, S_YK, S_YV, S_CTX, S_CTXQ1, S_DMIN, S_COUNT
};

struct PLA { float m[12]; float c[12]; float a[12]; };

// ---------------- device helpers ----------------

__device__ __forceinline__ float qscale(const unsigned* scal, int slot) {
  // reference: scale = max(maxabs / 127.0, 1e-8)
  return fmaxf(__uint_as_float(scal[slot]) / QMAXF, 1e-8f);
}

__device__ __forceinline__ void block_atomic_maxf(float v, unsigned* slot) {
  for (int off = 32; off > 0; off >>= 1) v = fmaxf(v, __shfl_xor(v, off, 64));
  __shared__ float red[4];
  int lane = threadIdx.x & 63, w = threadIdx.x >> 6;
  if (lane == 0) red[w] = v;
  __syncthreads();
  if (threadIdx.x == 0)
    atomicMax(slot, __float_as_uint(fmaxf(fmaxf(red[0], red[1]), fmaxf(red[2], red[3]))));
}

__device__ __forceinline__ int qpack4(float a0, float a1, float a2, float a3, float s) {
  int i0 = (int)fminf(fmaxf(rintf(a0 / s), -QMAXF), QMAXF);
  int i1 = (int)fminf(fmaxf(rintf(a1 / s), -QMAXF), QMAXF);
  int i2 = (int)fminf(fmaxf(rintf(a2 / s), -QMAXF), QMAXF);
  int i3 = (int)fminf(fmaxf(rintf(a3 / s), -QMAXF), QMAXF);
  return (i0 & 255) | ((i1 & 255) << 8) | ((i2 & 255) << 16) | ((i3 & 255) << 24);
}

__device__ __forceinline__ float pla_exp(float xc, const PLA& pla) {
  float mm = pla.m[0], cc = pla.c[0];
#pragma unroll
  for (int ii = 1; ii <= 10; ++ii) {   // idx clamped to <=10 (reference quirk)
    bool ge = xc >= pla.a[ii];
    mm = ge ? pla.m[ii] : mm;
    cc = ge ? pla.c[ii] : cc;
  }
  float e = mm * xc;   // no fma: contract off
  e = e + cc;
  return e;
}

__device__ __forceinline__ float fx_q3226(float x) {
  float sh = rintf(x * 67108864.0f);
  sh = fminf(fmaxf(sh, -2147483648.0f), 2147483648.0f);  // f32(2^31-1) == 2^31
  return sh * (1.0f / 67108864.0f);
}

// ---------------- tiny kernels ----------------

__global__ void zero_scal_kernel(unsigned* s) {
  if (threadIdx.x < 16) s[threadIdx.x] = (threadIdx.x == S_DMIN) ? 0x7f800000u : 0u;
}

__global__ __launch_bounds__(256) void maxabs4_kernel(const float4* __restrict__ x, int n4,
                                                      unsigned* __restrict__ slot) {
  float m = 0.0f;
  for (int i = blockIdx.x * 256 + threadIdx.x; i < n4; i += gridDim.x * 256) {
    float4 v = x[i];
    m = fmaxf(m, fmaxf(fmaxf(fabsf(v.x), fabsf(v.y)), fmaxf(fabsf(v.z), fabsf(v.w))));
  }
  block_atomic_maxf(m, slot);
}

// 4 weights in one launch: grid (576, 4), 576*256 == 768*768/4
__global__ __launch_bounds__(256) void maxabs_w4_kernel(const float4* __restrict__ w0, const float4* __restrict__ w1,
                                                        const float4* __restrict__ w2, const float4* __restrict__ w3,
                                                        unsigned* __restrict__ scal) {
  const float4* p = (blockIdx.y == 0) ? w0 : (blockIdx.y == 1) ? w1 : (blockIdx.y == 2) ? w2 : w3;
  int i = blockIdx.x * 256 + threadIdx.x;
  float4 v = p[i];
  float m = fmaxf(fmaxf(fabsf(v.x), fabsf(v.y)), fmaxf(fabsf(v.z), fabsf(v.w)));
  block_atomic_maxf(m, scal + S_WQ + blockIdx.y);
}

// 4 biases in one launch: grid 4 blocks
__global__ __launch_bounds__(256) void maxabs_bias_kernel(const float* __restrict__ b0, const float* __restrict__ b1,
                                                          const float* __restrict__ b2, const float* __restrict__ b3,
                                                          unsigned* __restrict__ scal) {
  const float* p = (blockIdx.x == 0) ? b0 : (blockIdx.x == 1) ? b1 : (blockIdx.x == 2) ? b2 : b3;
  float m = 0.0f;
  for (int i = threadIdx.x; i < 768; i += 256) m = fmaxf(m, fabsf(p[i]));
  block_atomic_maxf(m, scal + S_BQ + blockIdx.x);
}

__global__ __launch_bounds__(256) void quant4_kernel(const float4* __restrict__ x, int* __restrict__ q,
                                                     const unsigned* __restrict__ scal, int slot) {
  int i = blockIdx.x * 256 + threadIdx.x;   // exact grid
  float s = qscale(scal, slot);
  float4 v = x[i];
  q[i] = qpack4(v.x, v.y, v.z, v.w, s);
}

// 4 weights quant in one launch: grid (576, 4)
__global__ __launch_bounds__(256) void quant4_w_kernel(const float4* __restrict__ w0, const float4* __restrict__ w1,
                                                       const float4* __restrict__ w2, const float4* __restrict__ w3,
                                                       int* __restrict__ o0, int* __restrict__ o1,
                                                       int* __restrict__ o2, int* __restrict__ o3,
                                                       const unsigned* __restrict__ scal) {
  int which = blockIdx.y;
  const float4* p = (which == 0) ? w0 : (which == 1) ? w1 : (which == 2) ? w2 : w3;
  int* o = (which == 0) ? o0 : (which == 1) ? o1 : (which == 2) ? o2 : o3;
  int i = blockIdx.x * 256 + threadIdx.x;
  float s = qscale(scal, S_WQ + which);
  float4 v = p[i];
  o[i] = qpack4(v.x, v.y, v.z, v.w, s);
}

__global__ void qbias_kernel(const float* __restrict__ b, float* __restrict__ qb,
                             const unsigned* __restrict__ scal, int slotX, int slotW, int slotB) {
  int j = blockIdx.x * 256 + threadIdx.x;
  if (j >= 768) return;
  float in_scale = __uint_as_float(scal[slotX]) / QMAXF;   // no clamp (reference)
  float w_scale  = __uint_as_float(scal[slotW]) / QMAXF;
  float bias_scale = in_scale * w_scale;
  float tmax = __uint_as_float(scal[slotB]) / bias_scale;
  float st = fmaxf(tmax / QMAXF, 1e-8f);
  float t = b[j] / bias_scale;
  float qv = fminf(fmaxf(rintf(t / st), -127.0f), 127.0f) * st;
  qb[j] = qv * bias_scale;
}

// Y [B*S][768] -> int8 head layout [(b*12+h)][512][64], packed int writes
__global__ __launch_bounds__(256) void quant_heads_qk_kernel(const float* __restrict__ Y, int* __restrict__ q,
                                                             const unsigned* __restrict__ scal, int slot) {
  int i = blockIdx.x * 256 + threadIdx.x;  // over 786432 int4-groups, grid 3072
  float s = qscale(scal, slot);
  int d0 = (i & 15) * 4;
  int sI = (i >> 4) & 511;
  int bh = i >> 13;
  int h = bh % 12, b = bh / 12;
  const float* src = Y + ((size_t)(b * 512 + sI)) * 768 + h * 64 + d0;
  float4 v = *(const float4*)src;
  q[i] = qpack4(v.x, v.y, v.z, v.w, s);   // dest byte offset == 4*i == bh*32768 + sI*64 + d0
}

// V: quantize + transpose into [bh][64 d][512 s]
__global__ __launch_bounds__(256) void quant_heads_v_kernel(const float* __restrict__ Y, int8_t* __restrict__ q,
                                                            const unsigned* __restrict__ scal) {
  __shared__ int8_t T[64][68];
  int bh = blockIdx.x >> 3, sb = blockIdx.x & 7;   // grid 96*8
  int b = bh / 12, h = bh % 12;
  float s = qscale(scal, S_YV);
  int d = threadIdx.x & 63, sl = threadIdx.x >> 6;
#pragma unroll
  for (int i = 0; i < 16; ++i) {
    int s_local = i * 4 + sl;
    float y = Y[((size_t)(b * 512 + sb * 64 + s_local)) * 768 + h * 64 + d];
    float tq = fminf(fmaxf(rintf(y / s), -QMAXF), QMAXF);
    T[d][s_local] = (int8_t)tq;
  }
  __syncthreads();
  int s4 = (threadIdx.x & 15) * 4, dl = threadIdx.x >> 4;
#pragma unroll
  for (int i = 0; i < 4; ++i) {
    int d_ = i * 16 + dl;
    int packed = (T[d_][s4] & 255) | ((T[d_][s4 + 1] & 255) << 8) |
                 ((T[d_][s4 + 2] & 255) << 16) | ((T[d_][s4 + 3] & 255) << 24);
    *(int*)(q + (size_t)bh * 32768 + (size_t)d_ * 512 + sb * 64 + s4) = packed;
  }
}

// ---------------- MFMA int8 GEMM:  C[4096][768] = A[4096][768] . B[768][768]^T * sA*sB + bias ----------------

__global__ __launch_bounds__(256) void gemm_i8_mfma(const int8_t* __restrict__ A, const int8_t* __restrict__ Bm,
                                                    float* __restrict__ C, const float* __restrict__ bias,
                                                    unsigned* __restrict__ scal, int slotA, int slotB, int maxslot) {
  int t = threadIdx.x, lane = t & 63, w = t >> 6, l15 = lane & 15, kg = lane >> 4;
  int bm = blockIdx.y * 64, bn = blockIdx.x * 64;
  float sAB = qscale(scal, slotA) * qscale(scal, slotB);
  const int8_t* ap = A + (size_t)(bm + w * 16 + l15) * 768 + kg * 16;
  const int8_t* bp = Bm + (size_t)(bn + l15) * 768 + kg * 16;
  i32x4 acc[4] = {{0,0,0,0}, {0,0,0,0}, {0,0,0,0}, {0,0,0,0}};
#pragma unroll
  for (int kc = 0; kc < 768; kc += 64) {
    i32x4 af = *(const i32x4*)(ap + kc);
#pragma unroll
    for (int ct = 0; ct < 4; ++ct) {
      i32x4 bf = *(const i32x4*)(bp + (size_t)ct * 16 * 768 + kc);
      acc[ct] = __builtin_amdgcn_mfma_i32_16x16x64_i8(af, bf, acc[ct], 0, 0, 0);
    }
  }
  float am = 0.0f;
#pragma unroll
  for (int ct = 0; ct < 4; ++ct) {
    float bv = bias[bn + ct * 16 + l15];
#pragma unroll
    for (int r = 0; r < 4; ++r) {
      int row = bm + w * 16 + kg * 4 + r;                 // C/D: col=lane&15, row=(lane>>4)*4+reg
      float v = (float)acc[ct][r] * sAB;
      float yv = v + bv;
      C[(size_t)row * 768 + bn + ct * 16 + l15] = yv;
      am = fmaxf(am, fabsf(yv));
    }
  }
  if (maxslot >= 0) block_atomic_maxf(am, scal + maxslot);
}

// ---------------- attention: swapped QK^T (lane owns one query x 32 keys, register softmax) ----------------
// mfma(K_tile, Q_tile): D[key=kg*4+r (+16*tile)][query=lane&15]. Shared between both passes so the
// e-values / summation order are bit-identical.

__device__ __forceinline__ void attn_e_phase(const int8_t* __restrict__ qbase,
                                             const int8_t* __restrict__ kbase,
                                             int rb, float pref, const PLA& pla,
                                             float (&v)[8][4], float (*red)[16], float& denom) {
  int t = threadIdx.x, lane = t & 63, w = t >> 6, l15 = lane & 15, kg = lane >> 4;
  i32x4 zero = {0, 0, 0, 0};
  i32x4 qf = *(const i32x4*)(qbase + (size_t)(rb * 16 + l15) * 64 + kg * 16);
  i32x4 acc[8];
#pragma unroll
  for (int i = 0; i < 8; ++i) {
    i32x4 kf = *(const i32x4*)(kbase + (size_t)((w * 8 + i) * 16 + l15) * 64 + kg * 16);
    acc[i] = __builtin_amdgcn_mfma_i32_16x16x64_i8(kf, qf, zero, 0, 0, 0);
  }
  float mx = -3.4e38f;
#pragma unroll
  for (int i = 0; i < 8; ++i)
#pragma unroll
    for (int r = 0; r < 4; ++r) {
      v[i][r] = (float)acc[i][r] * pref;
      mx = fmaxf(mx, v[i][r]);
    }
  mx = fmaxf(mx, __shfl_xor(mx, 16, 64));
  mx = fmaxf(mx, __shfl_xor(mx, 32, 64));
  if (lane < 16) red[w][l15] = mx;
  __syncthreads();
  float gm = fmaxf(fmaxf(red[0][l15], red[1][l15]), fmaxf(red[2][l15], red[3][l15]));
  __syncthreads();
  float s = 0.0f;
#pragma unroll
  for (int i = 0; i < 8; ++i)
#pragma unroll
    for (int r = 0; r < 4; ++r) {
      float x = v[i][r] - gm;
      float xc = fminf(fmaxf(fx_q3226(x), -10.0f), 0.0f);
      float e = pla_exp(xc, pla);
      v[i][r] = e;
      s += e;
    }
  s += __shfl_xor(s, 16, 64);
  s += __shfl_xor(s, 32, 64);
  if (lane < 16) red[w][l15] = s;
  __syncthreads();
  denom = (((red[0][l15] + red[1][l15]) + red[2][l15]) + red[3][l15]) + 1e-9f;
}

// pass 1: only the global minimum denominator is needed. Since PLA(exp) is monotone increasing
// and every row contains xc==0 (its own max) with e == c[10] exactly, the global Q1.15 max is
// rint(32768 * c10 / denom_min): pmax comes from denom_min alone.
__global__ __launch_bounds__(256) void attn_pass1(const int8_t* __restrict__ qq,
                                                  const int8_t* __restrict__ qk,
                                                  unsigned* __restrict__ scal, PLA pla) {
  __shared__ float red[4][16];
  int rb = blockIdx.x & 31, bh = blockIdx.x >> 5;
  float pref = (qscale(scal, S_YQ) * qscale(scal, S_YK)) * 0.125f;
  float v[8][4];
  float denom;
  attn_e_phase(qq + (size_t)bh * 32768, qk + (size_t)bh * 32768, rb, pref, pla, v, red, denom);
  if (threadIdx.x < 64) {
    float dm = denom;
    dm = fminf(dm, __shfl_xor(dm, 1, 64));
    dm = fminf(dm, __shfl_xor(dm, 2, 64));
    dm = fminf(dm, __shfl_xor(dm, 4, 64));
    dm = fminf(dm, __shfl_xor(dm, 8, 64));
    if (threadIdx.x == 0) atomicMin(scal + S_DMIN, __float_as_uint(dm));  // denom>0: bit-min == float-min
  }
}

__global__ __launch_bounds__(256) void attn_pass2(const int8_t* __restrict__ qq,
                                                  const int8_t* __restrict__ qk,
                                                  const int8_t* __restrict__ vT,
                                                  unsigned* __restrict__ scal,
                                                  float* __restrict__ ctx, PLA pla) {
  __shared__ float red[4][16];
  __shared__ alignas(16) int8_t Ps[16][528];
  int rb = blockIdx.x & 31, bh = blockIdx.x >> 5;
  int b = bh / 12, h = bh % 12;
  float sq = qscale(scal, S_YQ), sk = qscale(scal, S_YK), sv = qscale(scal, S_YV);
  float pref = (sq * sk) * 0.125f;
  // derive prob quant scale from global denom_min (identical arithmetic to the per-element path)
  float dmin = __uint_as_float(scal[S_DMIN]);
  float smm = pla.c[10] / dmin;
  float q15m = fminf(fmaxf(rintf(smm * 32768.0f), -32768.0f), 32767.0f);
  float sp = fmaxf((q15m * (1.0f / 32768.0f)) / QMAXF, 1e-8f);
  float v[8][4];
  float denom;
  attn_e_phase(qq + (size_t)bh * 32768, qk + (size_t)bh * 32768, rb, pref, pla, v, red, denom);
  int t = threadIdx.x, lane = t & 63, w = t >> 6, l15 = lane & 15, kg = lane >> 4;
#pragma unroll
  for (int i = 0; i < 8; ++i) {
    uint32_t packed = 0;
#pragma unroll
    for (int r = 0; r < 4; ++r) {
      float sm = v[i][r] / denom;
      float q15 = fminf(fmaxf(rintf(sm * 32768.0f), -32768.0f), 32767.0f);
      float pv = q15 * (1.0f / 32768.0f);
      int qp = (int)fminf(fmaxf(rintf(pv / sp), -QMAXF), QMAXF);
      packed |= (uint32_t)(qp & 255) << (8 * r);
    }
    *(uint32_t*)&Ps[l15][(w * 8 + i) * 16 + kg * 4] = packed;   // 4 consecutive keys per lane
  }
  __syncthreads();
  // PV: ctx[q][d] = sum_k P[q][k] * V[k][d]  (A = P rows, B = vT rows)
  i32x4 pacc = {0, 0, 0, 0};
  const int8_t* vbase = vT + (size_t)bh * 32768 + (size_t)(w * 16 + l15) * 512;
#pragma unroll
  for (int ks = 0; ks < 8; ++ks) {
    i32x4 pf = *(const i32x4*)&Ps[l15][ks * 64 + kg * 16];
    i32x4 vf = *(const i32x4*)(vbase + ks * 64 + kg * 16);
    pacc = __builtin_amdgcn_mfma_i32_16x16x64_i8(pf, vf, pacc, 0, 0, 0);
  }
  float spv = sp * sv;
  float am = 0.0f;
#pragma unroll
  for (int r = 0; r < 4; ++r) {
    int srow = rb * 16 + kg * 4 + r;
    float val = (float)pacc[r] * spv;
    ctx[((size_t)(b * 512 + srow)) * 768 + h * 64 + w * 16 + l15] = val;
    am = fmaxf(am, fabsf(val));
  }
  block_atomic_maxf(am, scal + S_CTX);
}

// ---------------- ctx double-quant (vectorized) ----------------

__global__ __launch_bounds__(256) void ctx_q1_kernel(const float4* __restrict__ ctx, int* __restrict__ i1,
                                                     unsigned* __restrict__ scal) {
  int i = blockIdx.x * 256 + threadIdx.x;   // exact grid 3072
  float s1 = qscale(scal, S_CTX);
  float4 c = ctx[i];
  int q0 = (int)fminf(fmaxf(rintf(c.x / s1), -QMAXF), QMAXF);
  int q1 = (int)fminf(fmaxf(rintf(c.y / s1), -QMAXF), QMAXF);
  int q2 = (int)fminf(fmaxf(rintf(c.z / s1), -QMAXF), QMAXF);
  int q3 = (int)fminf(fmaxf(rintf(c.w / s1), -QMAXF), QMAXF);
  i1[i] = (q0 & 255) | ((q1 & 255) << 8) | ((q2 & 255) << 16) | ((q3 & 255) << 24);
  float am = fmaxf(fmaxf(fabsf((float)q0 * s1), fabsf((float)q1 * s1)),
                   fmaxf(fabsf((float)q2 * s1), fabsf((float)q3 * s1)));
  block_atomic_maxf(am, scal + S_CTXQ1);
}

__global__ __launch_bounds__(256) void ctx_q2_kernel(const int* __restrict__ i1, int* __restrict__ q2o,
                                                     const unsigned* __restrict__ scal) {
  int i = blockIdx.x * 256 + threadIdx.x;
  float s1 = qscale(scal, S_CTX);
  float s2 = qscale(scal, S_CTXQ1);
  int v = i1[i];
  int out = 0;
#pragma unroll
  for (int k = 0; k < 4; ++k) {
    float y = (float)((int8_t)(v >> (8 * k))) * s1;
    int qq = (int)fminf(fmaxf(rintf(y / s2), -QMAXF), QMAXF);
    out |= (qq & 255) << (8 * k);
  }
  q2o[i] = out;
}

// ---------------- host: PLA build (replicates np.polyfit degree-1 LS in f64) ----------------

static void build_pla(PLA& p) {
  double xs[1001], ys[1001];
  double step = 10.0 / 1000.0;
  for (int j = 0; j <= 1000; ++j) xs[j] = (double)j * step + (-10.0);
  xs[1000] = 0.0;
  for (int j = 0; j <= 1000; ++j) ys[j] = exp(xs[j]);
  double estep = 10.0 / 12.0;
  for (int i = 0; i < 12; ++i) {
    double a = (double)i * estep + (-10.0);
    double bb = (i + 1 == 12) ? 0.0 : (double)(i + 1) * estep + (-10.0);
    double n = 0, Sx = 0, Sy = 0, Sxx = 0, Sxy = 0;
    for (int j = 0; j <= 1000; ++j) {
      if (xs[j] >= a && xs[j] <= bb) {
        double x = xs[j], y = ys[j];
        n += 1.0; Sx += x; Sy += y; Sxx += x * x; Sxy += x * y;
      }
    }
    double det = n * Sxx - Sx * Sx;
    p.m[i] = (float)((n * Sxy - Sx * Sy) / det);
    p.c[i] = (float)((Sxx * Sy - Sx * Sxy) / det);
    p.a[i] = (float)a;
  }
}

// ---------------- launch ----------------

extern "C" void kernel_launch(void* const* d_in, const int* in_sizes, int n_in,
                              void* d_out, int out_size, void* d_ws, size_t ws_size,
                              hipStream_t stream) {
  const float* X  = (const float*)d_in[0];
  const float* Wq = (const float*)d_in[1];
  const float* bq = (const float*)d_in[2];
  const float* Wk = (const float*)d_in[3];
  const float* bk = (const float*)d_in[4];
  const float* Wv = (const float*)d_in[5];
  const float* bv = (const float*)d_in[6];
  const float* Wo = (const float*)d_in[7];
  const float* bo = (const float*)d_in[8];
  float* out = (float*)d_out;

  PLA pla;
  build_pla(pla);

  const int NX = 8 * 512 * 768;  // 3145728
  const int NW = 768 * 768;      // 589824
  const int NB = 768;

  uint8_t* ws = (uint8_t*)d_ws;
  size_t off = 0;
  auto alloc = [&](size_t bytes) -> void* {
    void* p = ws + off;
    off += (bytes + 255) & ~(size_t)255;
    return p;
  };
  unsigned* scal = (unsigned*)alloc(64 * 4);
  int8_t* qX  = (int8_t*)alloc(NX);
  int8_t* qWq = (int8_t*)alloc(NW);
  int8_t* qWk = (int8_t*)alloc(NW);
  int8_t* qWv = (int8_t*)alloc(NW);
  int8_t* qWo = (int8_t*)alloc(NW);
  float* qbq = (float*)alloc(NB * 4);
  float* qbk = (float*)alloc(NB * 4);
  float* qbv = (float*)alloc(NB * 4);
  float* qbo = (float*)alloc(NB * 4);
  float* Y   = (float*)alloc((size_t)NX * 4);   // reused as ctx
  int8_t* qq = (int8_t*)alloc(NX);
  int8_t* qk = (int8_t*)alloc(NX);
  int8_t* qvT = (int8_t*)alloc(NX);
  int8_t* i1    = qX;  // reuse: qX dead after QKV GEMMs
  int8_t* qctx2 = qq;  // reuse: qq dead after attention PV pass
  float* ctx    = Y;   // reuse: Y dead after quant_heads_v
  (void)ws_size; (void)n_in; (void)in_sizes; (void)out_size;

  zero_scal_kernel<<<1, 64, 0, stream>>>(scal);

  maxabs4_kernel<<<1024, 256, 0, stream>>>((const float4*)X, NX / 4, scal + S_X);
  maxabs_w4_kernel<<<dim3(576, 4), 256, 0, stream>>>((const float4*)Wq, (const float4*)Wk,
                                                     (const float4*)Wv, (const float4*)Wo, scal);
  maxabs_bias_kernel<<<4, 256, 0, stream>>>(bq, bk, bv, bo, scal);

  quant4_kernel<<<3072, 256, 0, stream>>>((const float4*)X, (int*)qX, scal, S_X);
  quant4_w_kernel<<<dim3(576, 4), 256, 0, stream>>>((const float4*)Wq, (const float4*)Wk,
                                                    (const float4*)Wv, (const float4*)Wo,
                                                    (int*)qWq, (int*)qWk, (int*)qWv, (int*)qWo, scal);

  qbias_kernel<<<3, 256, 0, stream>>>(bq, qbq, scal, S_X, S_WQ, S_BQ);
  qbias_kernel<<<3, 256, 0, stream>>>(bk, qbk, scal, S_X, S_WK, S_BK);
  qbias_kernel<<<3, 256, 0, stream>>>(bv, qbv, scal, S_X, S_WV, S_BV);

  dim3 ggrid(12, 64);
  gemm_i8_mfma<<<ggrid, 256, 0, stream>>>(qX, qWq, Y, qbq, scal, S_X, S_WQ, S_YQ);
  quant_heads_qk_kernel<<<3072, 256, 0, stream>>>(Y, (int*)qq, scal, S_YQ);
  gemm_i8_mfma<<<ggrid, 256, 0, stream>>>(qX, qWk, Y, qbk, scal, S_X, S_WK, S_YK);
  quant_heads_qk_kernel<<<3072, 256, 0, stream>>>(Y, (int*)qk, scal, S_YK);
  gemm_i8_mfma<<<ggrid, 256, 0, stream>>>(qX, qWv, Y, qbv, scal, S_X, S_WV, S_YV);
  quant_heads_v_kernel<<<768, 256, 0, stream>>>(Y, qvT, scal);

  attn_pass1<<<3072, 256, 0, stream>>>(qq, qk, scal, pla);
  attn_pass2<<<3072, 256, 0, stream>>>(qq, qk, qvT, scal, ctx, pla);

  ctx_q1_kernel<<<3072, 256, 0, stream>>>((const float4*)ctx, (int*)i1, scal);
  qbias_kernel<<<3, 256, 0, stream>>>(bo, qbo, scal, S_CTXQ1, S_WO, S_BO);
  ctx_q2_kernel<<<3072, 256, 0, stream>>>((const int*)i1, (int*)qctx2, scal);
  gemm_i8_mfma<<<ggrid, 256, 0, stream>>>(qctx2, qWo, out, qbo, scal, S_CTXQ1, S_WO, -1);
}

// Round 4
// 267.196 us; speedup vs baseline: 4.4887x; 1.1835x over previous
//
#include <hip/hip_runtime.h>
#include <cstdint>
#include <cmath>
#include <cstddef>

#pragma clang fp contract(off)

#define QMAXF 127.0f

typedef int i32x4 __attribute__((ext_vector_type(4)));

enum {
  S_X = 0, S_WQ, S_WK, S_WV, S_WO, S_BQ, S_BK, S_BV, S_BO,
  S_YQ, S_YK, S_YV, S_CTX, S_CTXQ1, S_DMIN, S_COUNT
};

struct PLA { float m[12]; float c[12]; float a[12]; };

// ---------------- device helpers ----------------

__device__ __forceinline__ float qscale(const unsigned* scal, int slot) {
  // reference: scale = max(maxabs / 127.0, 1e-8)
  return fmaxf(__uint_as_float(scal[slot]) / QMAXF, 1e-8f);
}

__device__ __forceinline__ void block_atomic_maxf(float v, unsigned* slot) {
  for (int off = 32; off > 0; off >>= 1) v = fmaxf(v, __shfl_xor(v, off, 64));
  __shared__ float red[4];
  int lane = threadIdx.x & 63, w = threadIdx.x >> 6;
  if (lane == 0) red[w] = v;
  __syncthreads();
  if (threadIdx.x == 0)
    atomicMax(slot, __float_as_uint(fmaxf(fmaxf(red[0], red[1]), fmaxf(red[2], red[3]))));
}

__device__ __forceinline__ int qpack4(float a0, float a1, float a2, float a3, float s) {
  int i0 = (int)fminf(fmaxf(rintf(a0 / s), -QMAXF), QMAXF);
  int i1 = (int)fminf(fmaxf(rintf(a1 / s), -QMAXF), QMAXF);
  int i2 = (int)fminf(fmaxf(rintf(a2 / s), -QMAXF), QMAXF);
  int i3 = (int)fminf(fmaxf(rintf(a3 / s), -QMAXF), QMAXF);
  return (i0 & 255) | ((i1 & 255) << 8) | ((i2 & 255) << 16) | ((i3 & 255) << 24);
}

__device__ __forceinline__ float pla_exp(float xc, const PLA& pla) {
  float mm = pla.m[0], cc = pla.c[0];
#pragma unroll
  for (int ii = 1; ii <= 10; ++ii) {   // idx clamped to <=10 (reference quirk)
    bool ge = xc >= pla.a[ii];
    mm = ge ? pla.m[ii] : mm;
    cc = ge ? pla.c[ii] : cc;
  }
  float e = mm * xc;   // no fma: contract off
  e = e + cc;
  return e;
}

__device__ __forceinline__ float fx_q3226(float x) {
  float sh = rintf(x * 67108864.0f);
  sh = fminf(fmaxf(sh, -2147483648.0f), 2147483648.0f);  // f32(2^31-1) == 2^31
  return sh * (1.0f / 67108864.0f);
}

__device__ __forceinline__ float fabs4max(float4 v) {
  return fmaxf(fmaxf(fabsf(v.x), fabsf(v.y)), fmaxf(fabsf(v.z), fabsf(v.w)));
}

// ---------------- fused maxabs: X + 4 weights + 4 biases, one launch ----------------
// grid 1604: [0,1024) X strided x3; [1024,1600) W (144 blocks each, x4); [1600,1604) biases

__global__ __launch_bounds__(256) void maxabs_all(const float4* __restrict__ X,
                                                  const float4* __restrict__ w0, const float4* __restrict__ w1,
                                                  const float4* __restrict__ w2, const float4* __restrict__ w3,
                                                  const float* __restrict__ b0, const float* __restrict__ b1,
                                                  const float* __restrict__ b2, const float* __restrict__ b3,
                                                  unsigned* __restrict__ scal) {
  int blk = blockIdx.x, t = threadIdx.x;
  float m = 0.0f;
  unsigned* slot;
  if (blk < 1024) {
    int i = blk * 256 + t;
#pragma unroll
    for (int k = 0; k < 3; ++k) m = fmaxf(m, fabs4max(X[i + k * 262144]));
    slot = scal + S_X;
  } else if (blk < 1600) {
    int which = (blk - 1024) / 144, j = (blk - 1024) % 144;
    const float4* p = which == 0 ? w0 : which == 1 ? w1 : which == 2 ? w2 : w3;
    int i = j * 256 + t;
#pragma unroll
    for (int k = 0; k < 4; ++k) m = fmaxf(m, fabs4max(p[i + k * 36864]));
    slot = scal + S_WQ + which;
  } else {
    int which = blk - 1600;
    const float* p = which == 0 ? b0 : which == 1 ? b1 : which == 2 ? b2 : b3;
    for (int i = t; i < 768; i += 256) m = fmaxf(m, fabsf(p[i]));
    slot = scal + S_BQ + which;
  }
  block_atomic_maxf(m, slot);
}

// ---------------- fused quant: X + 4 weights + qbias(q,k,v), one launch ----------------

__device__ __forceinline__ void qbias_body(const float* __restrict__ b, float* __restrict__ qb,
                                           const unsigned* __restrict__ scal, int slotX, int slotW, int slotB, int j) {
  if (j >= 768) return;
  float in_scale = __uint_as_float(scal[slotX]) / QMAXF;   // no clamp (reference)
  float w_scale  = __uint_as_float(scal[slotW]) / QMAXF;
  float bias_scale = in_scale * w_scale;
  float tmax = __uint_as_float(scal[slotB]) / bias_scale;
  float st = fmaxf(tmax / QMAXF, 1e-8f);
  float t = b[j] / bias_scale;
  float qv = fminf(fmaxf(rintf(t / st), -127.0f), 127.0f) * st;
  qb[j] = qv * bias_scale;
}

// grid 1609: [0,1024) X; [1024,1600) W; [1600,1609) qbias q/k/v
__global__ __launch_bounds__(256) void quant_all(const float4* __restrict__ X, int* __restrict__ qX,
                                                 const float4* __restrict__ w0, const float4* __restrict__ w1,
                                                 const float4* __restrict__ w2, const float4* __restrict__ w3,
                                                 int* __restrict__ o0, int* __restrict__ o1,
                                                 int* __restrict__ o2, int* __restrict__ o3,
                                                 const float* __restrict__ bq, const float* __restrict__ bk,
                                                 const float* __restrict__ bv,
                                                 float* __restrict__ qbq, float* __restrict__ qbk,
                                                 float* __restrict__ qbv,
                                                 const unsigned* __restrict__ scal) {
  int blk = blockIdx.x, t = threadIdx.x;
  if (blk < 1024) {
    float s = qscale(scal, S_X);
    int i = blk * 256 + t;
#pragma unroll
    for (int k = 0; k < 3; ++k) {
      float4 v = X[i + k * 262144];
      qX[i + k * 262144] = qpack4(v.x, v.y, v.z, v.w, s);
    }
  } else if (blk < 1600) {
    int which = (blk - 1024) / 144, j = (blk - 1024) % 144;
    const float4* p = which == 0 ? w0 : which == 1 ? w1 : which == 2 ? w2 : w3;
    int* o = which == 0 ? o0 : which == 1 ? o1 : which == 2 ? o2 : o3;
    float s = qscale(scal, S_WQ + which);
    int i = j * 256 + t;
#pragma unroll
    for (int k = 0; k < 4; ++k) {
      float4 v = p[i + k * 36864];
      o[i + k * 36864] = qpack4(v.x, v.y, v.z, v.w, s);
    }
  } else {
    int proj = (blk - 1600) / 3, part = (blk - 1600) % 3;
    int j = part * 256 + t;
    const float* b = proj == 0 ? bq : proj == 1 ? bk : bv;
    float* qb = proj == 0 ? qbq : proj == 1 ? qbk : qbv;
    qbias_body(b, qb, scal, S_X, S_WQ + proj, S_BQ + proj, j);
  }
}

// ---------------- MFMA int8 GEMM body ----------------

__device__ __forceinline__ void gemm_body(const int8_t* __restrict__ A, const int8_t* __restrict__ Bm,
                                          float* __restrict__ C, const float* __restrict__ bias,
                                          unsigned* __restrict__ scal, int slotA, int slotB, int maxslot) {
  int t = threadIdx.x, lane = t & 63, w = t >> 6, l15 = lane & 15, kg = lane >> 4;
  int bm = blockIdx.y * 64, bn = blockIdx.x * 64;
  float sAB = qscale(scal, slotA) * qscale(scal, slotB);
  const int8_t* ap = A + (size_t)(bm + w * 16 + l15) * 768 + kg * 16;
  const int8_t* bp = Bm + (size_t)(bn + l15) * 768 + kg * 16;
  i32x4 acc[4] = {{0,0,0,0}, {0,0,0,0}, {0,0,0,0}, {0,0,0,0}};
#pragma unroll
  for (int kc = 0; kc < 768; kc += 64) {
    i32x4 af = *(const i32x4*)(ap + kc);
#pragma unroll
    for (int ct = 0; ct < 4; ++ct) {
      i32x4 bf = *(const i32x4*)(bp + (size_t)ct * 16 * 768 + kc);
      acc[ct] = __builtin_amdgcn_mfma_i32_16x16x64_i8(af, bf, acc[ct], 0, 0, 0);
    }
  }
  float am = 0.0f;
#pragma unroll
  for (int ct = 0; ct < 4; ++ct) {
    float bv = bias[bn + ct * 16 + l15];
#pragma unroll
    for (int r = 0; r < 4; ++r) {
      int row = bm + w * 16 + kg * 4 + r;                 // C/D: col=lane&15, row=(lane>>4)*4+reg
      float v = (float)acc[ct][r] * sAB;
      float yv = v + bv;
      C[(size_t)row * 768 + bn + ct * 16 + l15] = yv;
      am = fmaxf(am, fabsf(yv));
    }
  }
  if (maxslot >= 0) block_atomic_maxf(am, scal + maxslot);
}

// fused QKV: grid (12, 64, 3)
__global__ __launch_bounds__(256) void gemm_qkv(const int8_t* __restrict__ qX,
                                                const int8_t* __restrict__ qWq, const int8_t* __restrict__ qWk,
                                                const int8_t* __restrict__ qWv,
                                                const float* __restrict__ qbq, const float* __restrict__ qbk,
                                                const float* __restrict__ qbv,
                                                float* __restrict__ Yq, float* __restrict__ Yk, float* __restrict__ Yv,
                                                unsigned* __restrict__ scal) {
  int z = blockIdx.z;
  const int8_t* Bm = z == 0 ? qWq : z == 1 ? qWk : qWv;
  const float* bias = z == 0 ? qbq : z == 1 ? qbk : qbv;
  float* C = z == 0 ? Yq : z == 1 ? Yk : Yv;
  gemm_body(qX, Bm, C, bias, scal, S_X, S_WQ + z, S_YQ + z);
}

__global__ __launch_bounds__(256) void gemm_proj(const int8_t* __restrict__ A, const int8_t* __restrict__ Bm,
                                                 float* __restrict__ C, const float* __restrict__ bias,
                                                 unsigned* __restrict__ scal, int slotA, int slotB, int maxslot) {
  gemm_body(A, Bm, C, bias, scal, slotA, slotB, maxslot);
}

// ---------------- head re-layout + quant ----------------

__device__ __forceinline__ void qheads_qk_body(const float* __restrict__ Y, int* __restrict__ q,
                                               const unsigned* __restrict__ scal, int slot, int i) {
  float s = qscale(scal, slot);
  int d0 = (i & 15) * 4;
  int sI = (i >> 4) & 511;
  int bh = i >> 13;
  int h = bh % 12, b = bh / 12;
  const float* src = Y + ((size_t)(b * 512 + sI)) * 768 + h * 64 + d0;
  float4 v = *(const float4*)src;
  q[i] = qpack4(v.x, v.y, v.z, v.w, s);   // dest byte offset == 4*i == bh*32768 + sI*64 + d0
}

__device__ __forceinline__ void qheads_v_body(const float* __restrict__ Y, int8_t* __restrict__ q,
                                              const unsigned* __restrict__ scal, int blkv) {
  __shared__ int8_t T[64][68];
  int bh = blkv >> 3, sb = blkv & 7;
  int b = bh / 12, h = bh % 12;
  float s = qscale(scal, S_YV);
  int d = threadIdx.x & 63, sl = threadIdx.x >> 6;
#pragma unroll
  for (int i = 0; i < 16; ++i) {
    int s_local = i * 4 + sl;
    float y = Y[((size_t)(b * 512 + sb * 64 + s_local)) * 768 + h * 64 + d];
    float tq = fminf(fmaxf(rintf(y / s), -QMAXF), QMAXF);
    T[d][s_local] = (int8_t)tq;
  }
  __syncthreads();
  int s4 = (threadIdx.x & 15) * 4, dl = threadIdx.x >> 4;
#pragma unroll
  for (int i = 0; i < 4; ++i) {
    int d_ = i * 16 + dl;
    int packed = (T[d_][s4] & 255) | ((T[d_][s4 + 1] & 255) << 8) |
                 ((T[d_][s4 + 2] & 255) << 16) | ((T[d_][s4 + 3] & 255) << 24);
    *(int*)(q + (size_t)bh * 32768 + (size_t)d_ * 512 + sb * 64 + s4) = packed;
  }
}

// fused: grid 6912 = 3072 Q + 3072 K + 768 V-transpose
__global__ __launch_bounds__(256) void quant_heads_all(const float* __restrict__ Yq, int* __restrict__ qq,
                                                       const float* __restrict__ Yk, int* __restrict__ qk,
                                                       const float* __restrict__ Yv, int8_t* __restrict__ qvT,
                                                       const unsigned* __restrict__ scal) {
  int blk = blockIdx.x;
  if (blk < 3072)      qheads_qk_body(Yq, qq, scal, S_YQ, blk * 256 + threadIdx.x);
  else if (blk < 6144) qheads_qk_body(Yk, qk, scal, S_YK, (blk - 3072) * 256 + threadIdx.x);
  else                 qheads_v_body(Yv, qvT, scal, blk - 6144);
}

// single-section variants (fallback path)
__global__ __launch_bounds__(256) void quant_heads_qk(const float* __restrict__ Y, int* __restrict__ q,
                                                      const unsigned* __restrict__ scal, int slot) {
  qheads_qk_body(Y, q, scal, slot, blockIdx.x * 256 + threadIdx.x);
}
__global__ __launch_bounds__(256) void quant_heads_v(const float* __restrict__ Y, int8_t* __restrict__ q,
                                                     const unsigned* __restrict__ scal) {
  qheads_v_body(Y, q, scal, blockIdx.x);
}

// ---------------- attention: swapped QK^T (lane owns one query x 32 keys, register softmax) ----------------

__device__ __forceinline__ void attn_e_phase(const int8_t* __restrict__ qbase,
                                             const int8_t* __restrict__ kbase,
                                             int rb, float pref, const PLA& pla,
                                             float (&v)[8][4], float (*red)[16], float& denom) {
  int t = threadIdx.x, lane = t & 63, w = t >> 6, l15 = lane & 15, kg = lane >> 4;
  i32x4 zero = {0, 0, 0, 0};
  i32x4 qf = *(const i32x4*)(qbase + (size_t)(rb * 16 + l15) * 64 + kg * 16);
  i32x4 acc[8];
#pragma unroll
  for (int i = 0; i < 8; ++i) {
    i32x4 kf = *(const i32x4*)(kbase + (size_t)((w * 8 + i) * 16 + l15) * 64 + kg * 16);
    acc[i] = __builtin_amdgcn_mfma_i32_16x16x64_i8(kf, qf, zero, 0, 0, 0);
  }
  float mx = -3.4e38f;
#pragma unroll
  for (int i = 0; i < 8; ++i)
#pragma unroll
    for (int r = 0; r < 4; ++r) {
      v[i][r] = (float)acc[i][r] * pref;
      mx = fmaxf(mx, v[i][r]);
    }
  mx = fmaxf(mx, __shfl_xor(mx, 16, 64));
  mx = fmaxf(mx, __shfl_xor(mx, 32, 64));
  if (lane < 16) red[w][l15] = mx;
  __syncthreads();
  float gm = fmaxf(fmaxf(red[0][l15], red[1][l15]), fmaxf(red[2][l15], red[3][l15]));
  __syncthreads();
  float s = 0.0f;
#pragma unroll
  for (int i = 0; i < 8; ++i)
#pragma unroll
    for (int r = 0; r < 4; ++r) {
      float x = v[i][r] - gm;
      float xc = fminf(fmaxf(fx_q3226(x), -10.0f), 0.0f);
      float e = pla_exp(xc, pla);
      v[i][r] = e;
      s += e;
    }
  s += __shfl_xor(s, 16, 64);
  s += __shfl_xor(s, 32, 64);
  if (lane < 16) red[w][l15] = s;
  __syncthreads();
  denom = (((red[0][l15] + red[1][l15]) + red[2][l15]) + red[3][l15]) + 1e-9f;
}

// pass1: computes e-phase ONCE; optionally stores exact q15 ints (int16 pairs, coalesced dwords).
// Global pmax comes from denom_min alone: pmax = rint(32768*c10/dmin) (PLA row-max at xc=0 is c10;
// validated R2 vs R3: identical absmax). dmin encoded as 0x7f800000-bits so memset-0 init works.
__global__ __launch_bounds__(256) void attn_pass1(const int8_t* __restrict__ qq,
                                                  const int8_t* __restrict__ qk,
                                                  int* __restrict__ q15w,
                                                  unsigned* __restrict__ scal, PLA pla) {
  __shared__ float red[4][16];
  int rb = blockIdx.x & 31, bh = blockIdx.x >> 5;
  float pref = (qscale(scal, S_YQ) * qscale(scal, S_YK)) * 0.125f;
  float v[8][4];
  float denom;
  attn_e_phase(qq + (size_t)bh * 32768, qk + (size_t)bh * 32768, rb, pref, pla, v, red, denom);
  int t = threadIdx.x;
  if (q15w) {
    int base = blockIdx.x * 4096;
#pragma unroll
    for (int i = 0; i < 8; ++i) {
      int q15i[4];
#pragma unroll
      for (int r = 0; r < 4; ++r) {
        float sm = v[i][r] / denom;
        float q15 = fminf(fmaxf(rintf(sm * 32768.0f), -32768.0f), 32767.0f);
        q15i[r] = (int)q15;
      }
      q15w[base + (i * 2 + 0) * 256 + t] = (q15i[0] & 0xffff) | (q15i[1] << 16);
      q15w[base + (i * 2 + 1) * 256 + t] = (q15i[2] & 0xffff) | (q15i[3] << 16);
    }
  }
  if (t < 64) {
    float dm = denom;
    dm = fminf(dm, __shfl_xor(dm, 1, 64));
    dm = fminf(dm, __shfl_xor(dm, 2, 64));
    dm = fminf(dm, __shfl_xor(dm, 4, 64));
    dm = fminf(dm, __shfl_xor(dm, 8, 64));
    if (t == 0) atomicMax(scal + S_DMIN, 0x7f800000u - __float_as_uint(dm));
  }
}

__device__ __forceinline__ float derive_sp(const unsigned* scal, const PLA& pla) {
  float dmin = __uint_as_float(0x7f800000u - scal[S_DMIN]);
  float smm = pla.c[10] / dmin;
  float q15m = fminf(fmaxf(rintf(smm * 32768.0f), -32768.0f), 32767.0f);
  return fmaxf((q15m * (1.0f / 32768.0f)) / QMAXF, 1e-8f);
}

__device__ __forceinline__ void attn_pv_tail(const int8_t* __restrict__ vT, int8_t (*Ps)[528],
                                             unsigned* __restrict__ scal, float* __restrict__ ctx,
                                             int rb, int bh, float sp) {
  int t = threadIdx.x, lane = t & 63, w = t >> 6, l15 = lane & 15, kg = lane >> 4;
  int b = bh / 12, h = bh % 12;
  float sv = qscale(scal, S_YV);
  i32x4 pacc = {0, 0, 0, 0};
  const int8_t* vbase = vT + (size_t)bh * 32768 + (size_t)(w * 16 + l15) * 512;
#pragma unroll
  for (int ks = 0; ks < 8; ++ks) {
    i32x4 pf = *(const i32x4*)&Ps[l15][ks * 64 + kg * 16];
    i32x4 vf = *(const i32x4*)(vbase + ks * 64 + kg * 16);
    pacc = __builtin_amdgcn_mfma_i32_16x16x64_i8(pf, vf, pacc, 0, 0, 0);
  }
  float spv = sp * sv;
  float am = 0.0f;
#pragma unroll
  for (int r = 0; r < 4; ++r) {
    int srow = rb * 16 + kg * 4 + r;
    float val = (float)pacc[r] * spv;
    ctx[((size_t)(b * 512 + srow)) * 768 + h * 64 + w * 16 + l15] = val;
    am = fmaxf(am, fabsf(val));
  }
  block_atomic_maxf(am, scal + S_CTX);
}

// fast pass2: load stored q15, quantize to int8, PV. No QK^T / softmax recompute.
__global__ __launch_bounds__(256) void attn_pass2_load(const int* __restrict__ q15r,
                                                       const int8_t* __restrict__ vT,
                                                       unsigned* __restrict__ scal,
                                                       float* __restrict__ ctx, PLA pla) {
  __shared__ alignas(16) int8_t Ps[16][528];
  int rb = blockIdx.x & 31, bh = blockIdx.x >> 5;
  float sp = derive_sp(scal, pla);
  int t = threadIdx.x, lane = t & 63, w = t >> 6, l15 = lane & 15, kg = lane >> 4;
  int base = blockIdx.x * 4096;
#pragma unroll
  for (int i = 0; i < 8; ++i) {
    int u01 = q15r[base + (i * 2 + 0) * 256 + t];
    int u23 = q15r[base + (i * 2 + 1) * 256 + t];
    int q15i[4] = { (int)(short)(u01 & 0xffff), u01 >> 16,
                    (int)(short)(u23 & 0xffff), u23 >> 16 };
    uint32_t packed = 0;
#pragma unroll
    for (int r = 0; r < 4; ++r) {
      float pv = (float)q15i[r] * (1.0f / 32768.0f);
      int qp = (int)fminf(fmaxf(rintf(pv / sp), -QMAXF), QMAXF);
      packed |= (uint32_t)(qp & 255) << (8 * r);
    }
    *(uint32_t*)&Ps[l15][(w * 8 + i) * 16 + kg * 4] = packed;
  }
  __syncthreads();
  attn_pv_tail(vT, Ps, scal, ctx, rb, bh, sp);
}

// fallback pass2: recompute e-phase (bit-identical), quantize, PV (R3 path)
__global__ __launch_bounds__(256) void attn_pass2_recompute(const int8_t* __restrict__ qq,
                                                            const int8_t* __restrict__ qk,
                                                            const int8_t* __restrict__ vT,
                                                            unsigned* __restrict__ scal,
                                                            float* __restrict__ ctx, PLA pla) {
  __shared__ float red[4][16];
  __shared__ alignas(16) int8_t Ps[16][528];
  int rb = blockIdx.x & 31, bh = blockIdx.x >> 5;
  float pref = (qscale(scal, S_YQ) * qscale(scal, S_YK)) * 0.125f;
  float sp = derive_sp(scal, pla);
  float v[8][4];
  float denom;
  attn_e_phase(qq + (size_t)bh * 32768, qk + (size_t)bh * 32768, rb, pref, pla, v, red, denom);
  int t = threadIdx.x, lane = t & 63, w = t >> 6, l15 = lane & 15, kg = lane >> 4;
#pragma unroll
  for (int i = 0; i < 8; ++i) {
    uint32_t packed = 0;
#pragma unroll
    for (int r = 0; r < 4; ++r) {
      float sm = v[i][r] / denom;
      float q15 = fminf(fmaxf(rintf(sm * 32768.0f), -32768.0f), 32767.0f);
      float pv = q15 * (1.0f / 32768.0f);
      int qp = (int)fminf(fmaxf(rintf(pv / sp), -QMAXF), QMAXF);
      packed |= (uint32_t)(qp & 255) << (8 * r);
    }
    *(uint32_t*)&Ps[l15][(w * 8 + i) * 16 + kg * 4] = packed;
  }
  __syncthreads();
  attn_pv_tail(vT, Ps, scal, ctx, rb, bh, sp);
}

// ---------------- ctx double-quant ----------------

__global__ __launch_bounds__(256) void ctx_q1_kernel(const float4* __restrict__ ctx, int* __restrict__ i1,
                                                     unsigned* __restrict__ scal) {
  int i = blockIdx.x * 256 + threadIdx.x;   // exact grid 3072
  float s1 = qscale(scal, S_CTX);
  float4 c = ctx[i];
  int q0 = (int)fminf(fmaxf(rintf(c.x / s1), -QMAXF), QMAXF);
  int q1 = (int)fminf(fmaxf(rintf(c.y / s1), -QMAXF), QMAXF);
  int q2 = (int)fminf(fmaxf(rintf(c.z / s1), -QMAXF), QMAXF);
  int q3 = (int)fminf(fmaxf(rintf(c.w / s1), -QMAXF), QMAXF);
  i1[i] = (q0 & 255) | ((q1 & 255) << 8) | ((q2 & 255) << 16) | ((q3 & 255) << 24);
  float am = fmaxf(fmaxf(fabsf((float)q0 * s1), fabsf((float)q1 * s1)),
                   fmaxf(fabsf((float)q2 * s1), fabsf((float)q3 * s1)));
  block_atomic_maxf(am, scal + S_CTXQ1);
}

// grid 3075: [0,3072) ctx requant; [3072,3075) qbias for O projection
__global__ __launch_bounds__(256) void ctx_q2_plus(const int* __restrict__ i1, int* __restrict__ q2o,
                                                   const float* __restrict__ bo, float* __restrict__ qbo,
                                                   const unsigned* __restrict__ scal) {
  int blk = blockIdx.x;
  if (blk < 3072) {
    int i = blk * 256 + threadIdx.x;
    float s1 = qscale(scal, S_CTX);
    float s2 = qscale(scal, S_CTXQ1);
    int v = i1[i];
    int out = 0;
#pragma unroll
    for (int k = 0; k < 4; ++k) {
      float y = (float)((int8_t)(v >> (8 * k))) * s1;
      int qq = (int)fminf(fmaxf(rintf(y / s2), -QMAXF), QMAXF);
      out |= (qq & 255) << (8 * k);
    }
    q2o[i] = out;
  } else {
    int j = (blk - 3072) * 256 + threadIdx.x;
    qbias_body(bo, qbo, scal, S_CTXQ1, S_WO, S_BO, j);
  }
}

// ---------------- host: PLA build (replicates np.polyfit degree-1 LS in f64) ----------------

static void build_pla(PLA& p) {
  double xs[1001], ys[1001];
  double step = 10.0 / 1000.0;
  for (int j = 0; j <= 1000; ++j) xs[j] = (double)j * step + (-10.0);
  xs[1000] = 0.0;
  for (int j = 0; j <= 1000; ++j) ys[j] = exp(xs[j]);
  double estep = 10.0 / 12.0;
  for (int i = 0; i < 12; ++i) {
    double a = (double)i * estep + (-10.0);
    double bb = (i + 1 == 12) ? 0.0 : (double)(i + 1) * estep + (-10.0);
    double n = 0, Sx = 0, Sy = 0, Sxx = 0, Sxy = 0;
    for (int j = 0; j <= 1000; ++j) {
      if (xs[j] >= a && xs[j] <= bb) {
        double x = xs[j], y = ys[j];
        n += 1.0; Sx += x; Sy += y; Sxx += x * x; Sxy += x * y;
      }
    }
    double det = n * Sxx - Sx * Sx;
    p.m[i] = (float)((n * Sxy - Sx * Sy) / det);
    p.c[i] = (float)((Sxx * Sy - Sx * Sxy) / det);
    p.a[i] = (float)a;
  }
}

// ---------------- launch ----------------

extern "C" void kernel_launch(void* const* d_in, const int* in_sizes, int n_in,
                              void* d_out, int out_size, void* d_ws, size_t ws_size,
                              hipStream_t stream) {
  const float* X  = (const float*)d_in[0];
  const float* Wq = (const float*)d_in[1];
  const float* bq = (const float*)d_in[2];
  const float* Wk = (const float*)d_in[3];
  const float* bk = (const float*)d_in[4];
  const float* Wv = (const float*)d_in[5];
  const float* bv = (const float*)d_in[6];
  const float* Wo = (const float*)d_in[7];
  const float* bo = (const float*)d_in[8];
  float* out = (float*)d_out;
  (void)n_in; (void)in_sizes; (void)out_size;

  PLA pla;
  build_pla(pla);

  const size_t NX = 8 * 512 * 768;   // 3145728
  const size_t NW = 768 * 768;       // 589824
  const size_t Q15_BYTES = 3072ull * 16384;  // 48 MiB
  const size_t Y3_BYTES = 3 * NX * 4;        // 37.7 MB

  uint8_t* ws = (uint8_t*)d_ws;
  size_t off = 0;
  auto alloc = [&](size_t bytes) -> void* {
    void* p = ws + off;
    off += (bytes + 255) & ~(size_t)255;
    return p;
  };

  unsigned* scal = (unsigned*)alloc(256);
  int8_t* qWq = (int8_t*)alloc(NW);
  int8_t* qWk = (int8_t*)alloc(NW);
  int8_t* qWv = (int8_t*)alloc(NW);
  int8_t* qWo = (int8_t*)alloc(NW);
  float* qbq = (float*)alloc(768 * 4);
  float* qbk = (float*)alloc(768 * 4);
  float* qbv = (float*)alloc(768 * 4);
  float* qbo = (float*)alloc(768 * 4);
  int8_t* qX = (int8_t*)alloc(NX);       // region CX: reused as i1
  int8_t* i1 = qX;

  // fast-path needs the big D (q15) + E (ctx) + F regions
  size_t fixed = off;
  size_t need_fast = fixed + Q15_BYTES + (4 * NX) + NX + 512;  // D + E + F
  bool fast = ws_size >= need_fast;

  hipMemsetAsync(scal, 0, 256, stream);

  if (fast) {
    uint8_t* D = (uint8_t*)alloc(Q15_BYTES);        // Yq|Yk|Yv then q15
    float* Yq = (float*)D;
    float* Yk = (float*)(D + NX * 4);
    float* Yv = (float*)(D + 2 * NX * 4);
    int* q15buf = (int*)D;
    uint8_t* E = (uint8_t*)alloc(4 * NX);           // qq|qk then ctx
    int8_t* qq = (int8_t*)E;
    int8_t* qk = (int8_t*)(E + NX);
    float* ctx = (float*)E;
    int8_t* qvT = (int8_t*)alloc(NX);               // then qctx2
    int8_t* qctx2 = qvT;

    maxabs_all<<<1604, 256, 0, stream>>>((const float4*)X, (const float4*)Wq, (const float4*)Wk,
                                         (const float4*)Wv, (const float4*)Wo, bq, bk, bv, bo, scal);
    quant_all<<<1609, 256, 0, stream>>>((const float4*)X, (int*)qX,
                                        (const float4*)Wq, (const float4*)Wk, (const float4*)Wv, (const float4*)Wo,
                                        (int*)qWq, (int*)qWk, (int*)qWv, (int*)qWo,
                                        bq, bk, bv, qbq, qbk, qbv, scal);
    gemm_qkv<<<dim3(12, 64, 3), 256, 0, stream>>>(qX, qWq, qWk, qWv, qbq, qbk, qbv, Yq, Yk, Yv, scal);
    quant_heads_all<<<6912, 256, 0, stream>>>(Yq, (int*)qq, Yk, (int*)qk, Yv, qvT, scal);
    attn_pass1<<<3072, 256, 0, stream>>>(qq, qk, q15buf, scal, pla);        // q15 overwrites Y (dead)
    attn_pass2_load<<<3072, 256, 0, stream>>>(q15buf, qvT, scal, ctx, pla); // ctx overwrites qq/qk (dead)
    ctx_q1_kernel<<<3072, 256, 0, stream>>>((const float4*)ctx, (int*)i1, scal);
    ctx_q2_plus<<<3075, 256, 0, stream>>>((const int*)i1, (int*)qctx2, bo, qbo, scal);
    gemm_proj<<<dim3(12, 64), 256, 0, stream>>>(qctx2, qWo, out, qbo, scal, S_CTXQ1, S_WO, -1);
  } else {
    // fallback: single-Y sequencing, e-phase recompute (27.7 MB proven footprint)
    float* Y = (float*)alloc(NX * 4);               // then ctx
    float* ctx = Y;
    int8_t* qq = (int8_t*)alloc(NX);                // then qctx2
    int8_t* qctx2 = qq;
    int8_t* qk = (int8_t*)alloc(NX);
    int8_t* qvT = (int8_t*)alloc(NX);

    maxabs_all<<<1604, 256, 0, stream>>>((const float4*)X, (const float4*)Wq, (const float4*)Wk,
                                         (const float4*)Wv, (const float4*)Wo, bq, bk, bv, bo, scal);
    quant_all<<<1609, 256, 0, stream>>>((const float4*)X, (int*)qX,
                                        (const float4*)Wq, (const float4*)Wk, (const float4*)Wv, (const float4*)Wo,
                                        (int*)qWq, (int*)qWk, (int*)qWv, (int*)qWo,
                                        bq, bk, bv, qbq, qbk, qbv, scal);
    gemm_proj<<<dim3(12, 64), 256, 0, stream>>>(qX, qWq, Y, qbq, scal, S_X, S_WQ, S_YQ);
    quant_heads_qk<<<3072, 256, 0, stream>>>(Y, (int*)qq, scal, S_YQ);
    gemm_proj<<<dim3(12, 64), 256, 0, stream>>>(qX, qWk, Y, qbk, scal, S_X, S_WK, S_YK);
    quant_heads_qk<<<3072, 256, 0, stream>>>(Y, (int*)qk, scal, S_YK);
    gemm_proj<<<dim3(12, 64), 256, 0, stream>>>(qX, qWv, Y, qbv, scal, S_X, S_WV, S_YV);
    quant_heads_v<<<768, 256, 0, stream>>>(Y, qvT, scal);
    attn_pass1<<<3072, 256, 0, stream>>>(qq, qk, (int*)nullptr, scal, pla);
    attn_pass2_recompute<<<3072, 256, 0, stream>>>(qq, qk, qvT, scal, ctx, pla);
    ctx_q1_kernel<<<3072, 256, 0, stream>>>((const float4*)ctx, (int*)i1, scal);
    ctx_q2_plus<<<3075, 256, 0, stream>>>((const int*)i1, (int*)qctx2, bo, qbo, scal);
    gemm_proj<<<dim3(12, 64), 256, 0, stream>>>(qctx2, qWo, out, qbo, scal, S_CTXQ1, S_WO, -1);
  }
}

// Round 5
// 213.418 us; speedup vs baseline: 5.6198x; 1.2520x over previous
//
#include <hip/hip_runtime.h>
#include <cstdint>
#include <cmath>
#include <cstddef>

#pragma clang fp contract(off)

#define QMAXF 127.0f

typedef int i32x4 __attribute__((ext_vector_type(4)));

enum {
  S_X = 0, S_WQ, S_WK, S_WV, S_WO, S_BQ, S_BK, S_BV, S_BO,
  S_YQ, S_YK, S_YV, S_CTX, S_CTXQ1, S_DMIN, S_COUNT
};

struct PLA { float m[12]; float c[12]; float a[12]; };

#define GLOAD_LDS16(gsrc, ldst) \
  __builtin_amdgcn_global_load_lds((const __attribute__((address_space(1))) void*)(gsrc), \
                                   (__attribute__((address_space(3))) void*)(ldst), 16, 0, 0)

// ---------------- device helpers ----------------

__device__ __forceinline__ float qscale(const unsigned* scal, int slot) {
  // reference: scale = max(maxabs / 127.0, 1e-8)
  return fmaxf(__uint_as_float(scal[slot]) / QMAXF, 1e-8f);
}

__device__ __forceinline__ void block_atomic_maxf(float v, unsigned* slot) {
  for (int off = 32; off > 0; off >>= 1) v = fmaxf(v, __shfl_xor(v, off, 64));
  __shared__ float red[4];
  int lane = threadIdx.x & 63, w = threadIdx.x >> 6;
  if (lane == 0) red[w] = v;
  __syncthreads();
  if (threadIdx.x == 0)
    atomicMax(slot, __float_as_uint(fmaxf(fmaxf(red[0], red[1]), fmaxf(red[2], red[3]))));
}

__device__ __forceinline__ int qpack4(float a0, float a1, float a2, float a3, float s) {
  int i0 = (int)fminf(fmaxf(rintf(a0 / s), -QMAXF), QMAXF);
  int i1 = (int)fminf(fmaxf(rintf(a1 / s), -QMAXF), QMAXF);
  int i2 = (int)fminf(fmaxf(rintf(a2 / s), -QMAXF), QMAXF);
  int i3 = (int)fminf(fmaxf(rintf(a3 / s), -QMAXF), QMAXF);
  return (i0 & 255) | ((i1 & 255) << 8) | ((i2 & 255) << 16) | ((i3 & 255) << 24);
}

__device__ __forceinline__ float fx_q3226(float x) {
  float sh = rintf(x * 67108864.0f);
  sh = fminf(fmaxf(sh, -2147483648.0f), 2147483648.0f);  // f32(2^31-1) == 2^31
  return sh * (1.0f / 67108864.0f);
}

__device__ __forceinline__ float fabs4max(float4 v) {
  return fmaxf(fmaxf(fabsf(v.x), fabsf(v.y)), fmaxf(fabsf(v.z), fabsf(v.w)));
}

// ---------------- fused maxabs: X + 4 weights + 4 biases, one launch ----------------

__global__ __launch_bounds__(256) void maxabs_all(const float4* __restrict__ X,
                                                  const float4* __restrict__ w0, const float4* __restrict__ w1,
                                                  const float4* __restrict__ w2, const float4* __restrict__ w3,
                                                  const float* __restrict__ b0, const float* __restrict__ b1,
                                                  const float* __restrict__ b2, const float* __restrict__ b3,
                                                  unsigned* __restrict__ scal) {
  int blk = blockIdx.x, t = threadIdx.x;
  float m = 0.0f;
  unsigned* slot;
  if (blk < 1024) {
    int i = blk * 256 + t;
#pragma unroll
    for (int k = 0; k < 3; ++k) m = fmaxf(m, fabs4max(X[i + k * 262144]));
    slot = scal + S_X;
  } else if (blk < 1600) {
    int which = (blk - 1024) / 144, j = (blk - 1024) % 144;
    const float4* p = which == 0 ? w0 : which == 1 ? w1 : which == 2 ? w2 : w3;
    int i = j * 256 + t;
#pragma unroll
    for (int k = 0; k < 4; ++k) m = fmaxf(m, fabs4max(p[i + k * 36864]));
    slot = scal + S_WQ + which;
  } else {
    int which = blk - 1600;
    const float* p = which == 0 ? b0 : which == 1 ? b1 : which == 2 ? b2 : b3;
    for (int i = t; i < 768; i += 256) m = fmaxf(m, fabsf(p[i]));
    slot = scal + S_BQ + which;
  }
  block_atomic_maxf(m, slot);
}

// ---------------- fused quant: X + 4 weights + qbias(q,k,v) ----------------

__device__ __forceinline__ void qbias_body(const float* __restrict__ b, float* __restrict__ qb,
                                           const unsigned* __restrict__ scal, int slotX, int slotW, int slotB, int j) {
  if (j >= 768) return;
  float in_scale = __uint_as_float(scal[slotX]) / QMAXF;   // no clamp (reference)
  float w_scale  = __uint_as_float(scal[slotW]) / QMAXF;
  float bias_scale = in_scale * w_scale;
  float tmax = __uint_as_float(scal[slotB]) / bias_scale;
  float st = fmaxf(tmax / QMAXF, 1e-8f);
  float t = b[j] / bias_scale;
  float qv = fminf(fmaxf(rintf(t / st), -127.0f), 127.0f) * st;
  qb[j] = qv * bias_scale;
}

__global__ __launch_bounds__(256) void quant_all(const float4* __restrict__ X, int* __restrict__ qX,
                                                 const float4* __restrict__ w0, const float4* __restrict__ w1,
                                                 const float4* __restrict__ w2, const float4* __restrict__ w3,
                                                 int* __restrict__ o0, int* __restrict__ o1,
                                                 int* __restrict__ o2, int* __restrict__ o3,
                                                 const float* __restrict__ bq, const float* __restrict__ bk,
                                                 const float* __restrict__ bv,
                                                 float* __restrict__ qbq, float* __restrict__ qbk,
                                                 float* __restrict__ qbv,
                                                 const unsigned* __restrict__ scal) {
  int blk = blockIdx.x, t = threadIdx.x;
  if (blk < 1024) {
    float s = qscale(scal, S_X);
    int i = blk * 256 + t;
#pragma unroll
    for (int k = 0; k < 3; ++k) {
      float4 v = X[i + k * 262144];
      qX[i + k * 262144] = qpack4(v.x, v.y, v.z, v.w, s);
    }
  } else if (blk < 1600) {
    int which = (blk - 1024) / 144, j = (blk - 1024) % 144;
    const float4* p = which == 0 ? w0 : which == 1 ? w1 : which == 2 ? w2 : w3;
    int* o = which == 0 ? o0 : which == 1 ? o1 : which == 2 ? o2 : o3;
    float s = qscale(scal, S_WQ + which);
    int i = j * 256 + t;
#pragma unroll
    for (int k = 0; k < 4; ++k) {
      float4 v = p[i + k * 36864];
      o[i + k * 36864] = qpack4(v.x, v.y, v.z, v.w, s);
    }
  } else {
    int proj = (blk - 1600) / 3, part = (blk - 1600) % 3;
    int j = part * 256 + t;
    const float* b = proj == 0 ? bq : proj == 1 ? bk : bv;
    float* qb = proj == 0 ? qbq : proj == 1 ? qbk : qbv;
    qbias_body(b, qb, scal, S_X, S_WQ + proj, S_BQ + proj, j);
  }
}

// ---------------- LDS-staged MFMA int8 GEMM ----------------
// C[4096][768] = A[4096][768] . B[768][768]^T * sA*sB + bias
// BM=128 BN=64 BK=128; 4 waves, wave w owns rows [32w,32w+32) x all 64 cols.
// XOR-swizzle (T2 / rule#21): LDS dest linear, global SOURCE pre-swizzled, ds_read swizzled.
// Fragment/output layout identical to R2-R4 proven 16x16x64 path.

__device__ __forceinline__ void gemm_body(const int8_t* __restrict__ A, const int8_t* __restrict__ Bm,
                                          float* __restrict__ C, const float* __restrict__ bias,
                                          unsigned* __restrict__ scal, int slotA, int slotB, int maxslot) {
  __shared__ int8_t Al[16384];   // [128 rows][128 K-bytes], row r holds A[r][col ^ ((r&7)<<4)]
  __shared__ int8_t Bl[8192];    // [64 rows][128 K-bytes]
  int t = threadIdx.x, lane = t & 63, w = t >> 6, l15 = lane & 15, kg4 = lane >> 4;
  int bm = blockIdx.y * 128, bn = blockIdx.x * 64;
  float sAB = qscale(scal, slotA) * qscale(scal, slotB);
  int srow = t >> 3, scol = (t & 7) * 16;
  int ssw = scol ^ ((srow & 7) << 4);     // (j*32) % 8 == 0 -> same swizzle every issue
  i32x4 acc[2][4];
#pragma unroll
  for (int rt = 0; rt < 2; ++rt)
#pragma unroll
    for (int ct = 0; ct < 4; ++ct)
#pragma unroll
      for (int r = 0; r < 4; ++r) acc[rt][ct][r] = 0;

  for (int kt = 0; kt < 6; ++kt) {
    int kc = kt * 128;
#pragma unroll
    for (int j = 0; j < 4; ++j) {   // A: 4 x 4KB issues, LDS dest linear in t
      int r = j * 32 + srow;
      GLOAD_LDS16(A + (size_t)(bm + r) * 768 + kc + ssw, Al + r * 128 + scol);
    }
#pragma unroll
    for (int j = 0; j < 2; ++j) {   // B: 2 x 4KB issues
      int r = j * 32 + srow;
      GLOAD_LDS16(Bm + (size_t)(bn + r) * 768 + kc + ssw, Bl + r * 128 + scol);
    }
    __syncthreads();                // drains vmcnt: staged tile visible
#pragma unroll
    for (int kg = 0; kg < 2; ++kg) {
      int kcol = kg * 64 + kg4 * 16;
      i32x4 af[2], bf[4];
#pragma unroll
      for (int rt = 0; rt < 2; ++rt) {
        int ar = w * 32 + rt * 16 + l15;
        af[rt] = *(const i32x4*)(Al + ar * 128 + (kcol ^ ((ar & 7) << 4)));
      }
#pragma unroll
      for (int ct = 0; ct < 4; ++ct) {
        int br = ct * 16 + l15;
        bf[ct] = *(const i32x4*)(Bl + br * 128 + (kcol ^ ((br & 7) << 4)));
      }
#pragma unroll
      for (int rt = 0; rt < 2; ++rt)
#pragma unroll
        for (int ct = 0; ct < 4; ++ct)
          acc[rt][ct] = __builtin_amdgcn_mfma_i32_16x16x64_i8(af[rt], bf[ct], acc[rt][ct], 0, 0, 0);
    }
    __syncthreads();                // all waves done reading before next stage overwrites
  }
  float am = 0.0f;
#pragma unroll
  for (int rt = 0; rt < 2; ++rt)
#pragma unroll
    for (int ct = 0; ct < 4; ++ct) {
      int col = bn + ct * 16 + l15;
      float bv = bias[col];
#pragma unroll
      for (int r = 0; r < 4; ++r) {
        int row = bm + w * 32 + rt * 16 + kg4 * 4 + r;   // C/D: col=lane&15, row=(lane>>4)*4+reg
        float v = (float)acc[rt][ct][r] * sAB;
        float yv = v + bv;
        C[(size_t)row * 768 + col] = yv;
        am = fmaxf(am, fabsf(yv));
      }
    }
  if (maxslot >= 0) block_atomic_maxf(am, scal + maxslot);
}

// fused QKV: grid (12, 32, 3)
__global__ __launch_bounds__(256) void gemm_qkv(const int8_t* __restrict__ qX,
                                                const int8_t* __restrict__ qWq, const int8_t* __restrict__ qWk,
                                                const int8_t* __restrict__ qWv,
                                                const float* __restrict__ qbq, const float* __restrict__ qbk,
                                                const float* __restrict__ qbv,
                                                float* __restrict__ Yq, float* __restrict__ Yk, float* __restrict__ Yv,
                                                unsigned* __restrict__ scal) {
  int z = blockIdx.z;
  const int8_t* Bm = z == 0 ? qWq : z == 1 ? qWk : qWv;
  const float* bias = z == 0 ? qbq : z == 1 ? qbk : qbv;
  float* C = z == 0 ? Yq : z == 1 ? Yk : Yv;
  gemm_body(qX, Bm, C, bias, scal, S_X, S_WQ + z, S_YQ + z);
}

__global__ __launch_bounds__(256) void gemm_proj(const int8_t* __restrict__ A, const int8_t* __restrict__ Bm,
                                                 float* __restrict__ C, const float* __restrict__ bias,
                                                 unsigned* __restrict__ scal, int slotA, int slotB, int maxslot) {
  gemm_body(A, Bm, C, bias, scal, slotA, slotB, maxslot);
}

// ---------------- head re-layout + quant ----------------

__device__ __forceinline__ void qheads_qk_body(const float* __restrict__ Y, int* __restrict__ q,
                                               const unsigned* __restrict__ scal, int slot, int i) {
  float s = qscale(scal, slot);
  int d0 = (i & 15) * 4;
  int sI = (i >> 4) & 511;
  int bh = i >> 13;
  int h = bh % 12, b = bh / 12;
  const float* src = Y + ((size_t)(b * 512 + sI)) * 768 + h * 64 + d0;
  float4 v = *(const float4*)src;
  q[i] = qpack4(v.x, v.y, v.z, v.w, s);   // dest byte offset == 4*i == bh*32768 + sI*64 + d0
}

__device__ __forceinline__ void qheads_v_body(const float* __restrict__ Y, int8_t* __restrict__ q,
                                              const unsigned* __restrict__ scal, int blkv) {
  __shared__ int8_t T[64][68];
  int bh = blkv >> 3, sb = blkv & 7;
  int b = bh / 12, h = bh % 12;
  float s = qscale(scal, S_YV);
  int d = threadIdx.x & 63, sl = threadIdx.x >> 6;
#pragma unroll
  for (int i = 0; i < 16; ++i) {
    int s_local = i * 4 + sl;
    float y = Y[((size_t)(b * 512 + sb * 64 + s_local)) * 768 + h * 64 + d];
    float tq = fminf(fmaxf(rintf(y / s), -QMAXF), QMAXF);
    T[d][s_local] = (int8_t)tq;
  }
  __syncthreads();
  int s4 = (threadIdx.x & 15) * 4, dl = threadIdx.x >> 4;
#pragma unroll
  for (int i = 0; i < 4; ++i) {
    int d_ = i * 16 + dl;
    int packed = (T[d_][s4] & 255) | ((T[d_][s4 + 1] & 255) << 8) |
                 ((T[d_][s4 + 2] & 255) << 16) | ((T[d_][s4 + 3] & 255) << 24);
    *(int*)(q + (size_t)bh * 32768 + (size_t)d_ * 512 + sb * 64 + s4) = packed;
  }
}

__global__ __launch_bounds__(256) void quant_heads_all(const float* __restrict__ Yq, int* __restrict__ qq,
                                                       const float* __restrict__ Yk, int* __restrict__ qk,
                                                       const float* __restrict__ Yv, int8_t* __restrict__ qvT,
                                                       const unsigned* __restrict__ scal) {
  int blk = blockIdx.x;
  if (blk < 3072)      qheads_qk_body(Yq, qq, scal, S_YQ, blk * 256 + threadIdx.x);
  else if (blk < 6144) qheads_qk_body(Yk, qk, scal, S_YK, (blk - 3072) * 256 + threadIdx.x);
  else                 qheads_v_body(Yv, qvT, scal, blk - 6144);
}

__global__ __launch_bounds__(256) void quant_heads_qk(const float* __restrict__ Y, int* __restrict__ q,
                                                      const unsigned* __restrict__ scal, int slot) {
  qheads_qk_body(Y, q, scal, slot, blockIdx.x * 256 + threadIdx.x);
}
__global__ __launch_bounds__(256) void quant_heads_v(const float* __restrict__ Y, int8_t* __restrict__ q,
                                                     const unsigned* __restrict__ scal) {
  qheads_v_body(Y, q, scal, blockIdx.x);
}

// ---------------- attention: swapped QK^T + register softmax + LDS PLA lookup ----------------
// Interval index: arithmetic estimate + exact +-1 boundary correction vs f32 edges ==
// clip(searchsorted(PLA_A, xc, 'right')-1, 0, 10) exactly (estimate error << 1 interval).

__device__ __forceinline__ void attn_e_phase(const int8_t* __restrict__ qbase,
                                             const int8_t* __restrict__ kbase,
                                             int rb, float pref, const PLA& pla,
                                             float (&v)[8][4], float (*red)[16], float& denom) {
  __shared__ float ae[12];
  __shared__ float2 mcs[11];
  int t = threadIdx.x, lane = t & 63, w = t >> 6, l15 = lane & 15, kg = lane >> 4;
  if (t < 12) ae[t] = pla.a[t];
  if (t < 11) mcs[t] = make_float2(pla.m[t], pla.c[t]);
  i32x4 zero = {0, 0, 0, 0};
  i32x4 qf = *(const i32x4*)(qbase + (size_t)(rb * 16 + l15) * 64 + kg * 16);
  i32x4 acc[8];
#pragma unroll
  for (int i = 0; i < 8; ++i) {
    i32x4 kf = *(const i32x4*)(kbase + (size_t)((w * 8 + i) * 16 + l15) * 64 + kg * 16);
    acc[i] = __builtin_amdgcn_mfma_i32_16x16x64_i8(kf, qf, zero, 0, 0, 0);
  }
  float mx = -3.4e38f;
#pragma unroll
  for (int i = 0; i < 8; ++i)
#pragma unroll
    for (int r = 0; r < 4; ++r) {
      v[i][r] = (float)acc[i][r] * pref;
      mx = fmaxf(mx, v[i][r]);
    }
  mx = fmaxf(mx, __shfl_xor(mx, 16, 64));
  mx = fmaxf(mx, __shfl_xor(mx, 32, 64));
  if (lane < 16) red[w][l15] = mx;
  __syncthreads();                     // also covers ae/mcs init
  float gm = fmaxf(fmaxf(red[0][l15], red[1][l15]), fmaxf(red[2][l15], red[3][l15]));
  __syncthreads();
  float s = 0.0f;
#pragma unroll
  for (int i = 0; i < 8; ++i)
#pragma unroll
    for (int r = 0; r < 4; ++r) {
      float x = v[i][r] - gm;
      float xc = fminf(fmaxf(fx_q3226(x), -10.0f), 0.0f);
      float tf = (xc + 10.0f) * 1.2f;
      int i0 = (int)tf;
      i0 = i0 > 10 ? 10 : i0;
      float elo = ae[i0], ehi = ae[i0 + 1];
      int idx = i0 + ((i0 < 10 && xc >= ehi) ? 1 : 0) - ((xc < elo) ? 1 : 0);
      float2 mc = mcs[idx];
      float e = mc.x * xc;   // no fma: contract off
      e = e + mc.y;
      v[i][r] = e;
      s += e;
    }
  s += __shfl_xor(s, 16, 64);
  s += __shfl_xor(s, 32, 64);
  if (lane < 16) red[w][l15] = s;
  __syncthreads();
  denom = (((red[0][l15] + red[1][l15]) + red[2][l15]) + red[3][l15]) + 1e-9f;
}

// pass1: e-phase ONCE; stores exact q15 ints. pmax derives from denom_min (row-max e == c[10]).
__global__ __launch_bounds__(256) void attn_pass1(const int8_t* __restrict__ qq,
                                                  const int8_t* __restrict__ qk,
                                                  int* __restrict__ q15w,
                                                  unsigned* __restrict__ scal, PLA pla) {
  __shared__ float red[4][16];
  int rb = blockIdx.x & 31, bh = blockIdx.x >> 5;
  float pref = (qscale(scal, S_YQ) * qscale(scal, S_YK)) * 0.125f;
  float v[8][4];
  float denom;
  attn_e_phase(qq + (size_t)bh * 32768, qk + (size_t)bh * 32768, rb, pref, pla, v, red, denom);
  int t = threadIdx.x;
  if (q15w) {
    int base = blockIdx.x * 4096;
#pragma unroll
    for (int i = 0; i < 8; ++i) {
      int q15i[4];
#pragma unroll
      for (int r = 0; r < 4; ++r) {
        float sm = v[i][r] / denom;
        float q15 = fminf(fmaxf(rintf(sm * 32768.0f), -32768.0f), 32767.0f);
        q15i[r] = (int)q15;
      }
      q15w[base + (i * 2 + 0) * 256 + t] = (q15i[0] & 0xffff) | (q15i[1] << 16);
      q15w[base + (i * 2 + 1) * 256 + t] = (q15i[2] & 0xffff) | (q15i[3] << 16);
    }
  }
  if (t < 64) {
    float dm = denom;
    dm = fminf(dm, __shfl_xor(dm, 1, 64));
    dm = fminf(dm, __shfl_xor(dm, 2, 64));
    dm = fminf(dm, __shfl_xor(dm, 4, 64));
    dm = fminf(dm, __shfl_xor(dm, 8, 64));
    if (t == 0) atomicMax(scal + S_DMIN, 0x7f800000u - __float_as_uint(dm));
  }
}

__device__ __forceinline__ float derive_sp(const unsigned* scal, const PLA& pla) {
  float dmin = __uint_as_float(0x7f800000u - scal[S_DMIN]);
  float smm = pla.c[10] / dmin;
  float q15m = fminf(fmaxf(rintf(smm * 32768.0f), -32768.0f), 32767.0f);
  return fmaxf((q15m * (1.0f / 32768.0f)) / QMAXF, 1e-8f);
}

__device__ __forceinline__ void attn_pv_tail(const int8_t* __restrict__ vT, int8_t (*Ps)[528],
                                             unsigned* __restrict__ scal, float* __restrict__ ctx,
                                             int rb, int bh, float sp) {
  int t = threadIdx.x, lane = t & 63, w = t >> 6, l15 = lane & 15, kg = lane >> 4;
  int b = bh / 12, h = bh % 12;
  float sv = qscale(scal, S_YV);
  i32x4 pacc = {0, 0, 0, 0};
  const int8_t* vbase = vT + (size_t)bh * 32768 + (size_t)(w * 16 + l15) * 512;
#pragma unroll
  for (int ks = 0; ks < 8; ++ks) {
    i32x4 pf = *(const i32x4*)&Ps[l15][ks * 64 + kg * 16];
    i32x4 vf = *(const i32x4*)(vbase + ks * 64 + kg * 16);
    pacc = __builtin_amdgcn_mfma_i32_16x16x64_i8(pf, vf, pacc, 0, 0, 0);
  }
  float spv = sp * sv;
  float am = 0.0f;
#pragma unroll
  for (int r = 0; r < 4; ++r) {
    int srow = rb * 16 + kg * 4 + r;
    float val = (float)pacc[r] * spv;
    ctx[((size_t)(b * 512 + srow)) * 768 + h * 64 + w * 16 + l15] = val;
    am = fmaxf(am, fabsf(val));
  }
  block_atomic_maxf(am, scal + S_CTX);
}

__global__ __launch_bounds__(256) void attn_pass2_load(const int* __restrict__ q15r,
                                                       const int8_t* __restrict__ vT,
                                                       unsigned* __restrict__ scal,
                                                       float* __restrict__ ctx, PLA pla) {
  __shared__ alignas(16) int8_t Ps[16][528];
  int rb = blockIdx.x & 31, bh = blockIdx.x >> 5;
  float sp = derive_sp(scal, pla);
  int t = threadIdx.x, lane = t & 63, w = t >> 6, l15 = lane & 15, kg = lane >> 4;
  int base = blockIdx.x * 4096;
#pragma unroll
  for (int i = 0; i < 8; ++i) {
    int u01 = q15r[base + (i * 2 + 0) * 256 + t];
    int u23 = q15r[base + (i * 2 + 1) * 256 + t];
    int q15i[4] = { (int)(short)(u01 & 0xffff), u01 >> 16,
                    (int)(short)(u23 & 0xffff), u23 >> 16 };
    uint32_t packed = 0;
#pragma unroll
    for (int r = 0; r < 4; ++r) {
      float pv = (float)q15i[r] * (1.0f / 32768.0f);
      int qp = (int)fminf(fmaxf(rintf(pv / sp), -QMAXF), QMAXF);
      packed |= (uint32_t)(qp & 255) << (8 * r);
    }
    *(uint32_t*)&Ps[l15][(w * 8 + i) * 16 + kg * 4] = packed;
  }
  __syncthreads();
  attn_pv_tail(vT, Ps, scal, ctx, rb, bh, sp);
}

__global__ __launch_bounds__(256) void attn_pass2_recompute(const int8_t* __restrict__ qq,
                                                            const int8_t* __restrict__ qk,
                                                            const int8_t* __restrict__ vT,
                                                            unsigned* __restrict__ scal,
                                                            float* __restrict__ ctx, PLA pla) {
  __shared__ float red[4][16];
  __shared__ alignas(16) int8_t Ps[16][528];
  int rb = blockIdx.x & 31, bh = blockIdx.x >> 5;
  float pref = (qscale(scal, S_YQ) * qscale(scal, S_YK)) * 0.125f;
  float sp = derive_sp(scal, pla);
  float v[8][4];
  float denom;
  attn_e_phase(qq + (size_t)bh * 32768, qk + (size_t)bh * 32768, rb, pref, pla, v, red, denom);
  int t = threadIdx.x, lane = t & 63, w = t >> 6, l15 = lane & 15, kg = lane >> 4;
#pragma unroll
  for (int i = 0; i < 8; ++i) {
    uint32_t packed = 0;
#pragma unroll
    for (int r = 0; r < 4; ++r) {
      float sm = v[i][r] / denom;
      float q15 = fminf(fmaxf(rintf(sm * 32768.0f), -32768.0f), 32767.0f);
      float pv = q15 * (1.0f / 32768.0f);
      int qp = (int)fminf(fmaxf(rintf(pv / sp), -QMAXF), QMAXF);
      packed |= (uint32_t)(qp & 255) << (8 * r);
    }
    *(uint32_t*)&Ps[l15][(w * 8 + i) * 16 + kg * 4] = packed;
  }
  __syncthreads();
  attn_pv_tail(vT, Ps, scal, ctx, rb, bh, sp);
}

// ---------------- ctx double-quant ----------------

__global__ __launch_bounds__(256) void ctx_q1_kernel(const float4* __restrict__ ctx, int* __restrict__ i1,
                                                     unsigned* __restrict__ scal) {
  int i = blockIdx.x * 256 + threadIdx.x;   // exact grid 3072
  float s1 = qscale(scal, S_CTX);
  float4 c = ctx[i];
  int q0 = (int)fminf(fmaxf(rintf(c.x / s1), -QMAXF), QMAXF);
  int q1 = (int)fminf(fmaxf(rintf(c.y / s1), -QMAXF), QMAXF);
  int q2 = (int)fminf(fmaxf(rintf(c.z / s1), -QMAXF), QMAXF);
  int q3 = (int)fminf(fmaxf(rintf(c.w / s1), -QMAXF), QMAXF);
  i1[i] = (q0 & 255) | ((q1 & 255) << 8) | ((q2 & 255) << 16) | ((q3 & 255) << 24);
  float am = fmaxf(fmaxf(fabsf((float)q0 * s1), fabsf((float)q1 * s1)),
                   fmaxf(fabsf((float)q2 * s1), fabsf((float)q3 * s1)));
  block_atomic_maxf(am, scal + S_CTXQ1);
}

__global__ __launch_bounds__(256) void ctx_q2_plus(const int* __restrict__ i1, int* __restrict__ q2o,
                                                   const float* __restrict__ bo, float* __restrict__ qbo,
                                                   const unsigned* __restrict__ scal) {
  int blk = blockIdx.x;
  if (blk < 3072) {
    int i = blk * 256 + threadIdx.x;
    float s1 = qscale(scal, S_CTX);
    float s2 = qscale(scal, S_CTXQ1);
    int v = i1[i];
    int out = 0;
#pragma unroll
    for (int k = 0; k < 4; ++k) {
      float y = (float)((int8_t)(v >> (8 * k))) * s1;
      int qq = (int)fminf(fmaxf(rintf(y / s2), -QMAXF), QMAXF);
      out |= (qq & 255) << (8 * k);
    }
    q2o[i] = out;
  } else {
    int j = (blk - 3072) * 256 + threadIdx.x;
    qbias_body(bo, qbo, scal, S_CTXQ1, S_WO, S_BO, j);
  }
}

// ---------------- host: PLA build (replicates np.polyfit degree-1 LS in f64) ----------------

static void build_pla(PLA& p) {
  double xs[1001], ys[1001];
  double step = 10.0 / 1000.0;
  for (int j = 0; j <= 1000; ++j) xs[j] = (double)j * step + (-10.0);
  xs[1000] = 0.0;
  for (int j = 0; j <= 1000; ++j) ys[j] = exp(xs[j]);
  double estep = 10.0 / 12.0;
  for (int i = 0; i < 12; ++i) {
    double a = (double)i * estep + (-10.0);
    double bb = (i + 1 == 12) ? 0.0 : (double)(i + 1) * estep + (-10.0);
    double n = 0, Sx = 0, Sy = 0, Sxx = 0, Sxy = 0;
    for (int j = 0; j <= 1000; ++j) {
      if (xs[j] >= a && xs[j] <= bb) {
        double x = xs[j], y = ys[j];
        n += 1.0; Sx += x; Sy += y; Sxx += x * x; Sxy += x * y;
      }
    }
    double det = n * Sxx - Sx * Sx;
    p.m[i] = (float)((n * Sxy - Sx * Sy) / det);
    p.c[i] = (float)((Sxx * Sy - Sx * Sxy) / det);
    p.a[i] = (float)a;
  }
}

// ---------------- launch ----------------

extern "C" void kernel_launch(void* const* d_in, const int* in_sizes, int n_in,
                              void* d_out, int out_size, void* d_ws, size_t ws_size,
                              hipStream_t stream) {
  const float* X  = (const float*)d_in[0];
  const float* Wq = (const float*)d_in[1];
  const float* bq = (const float*)d_in[2];
  const float* Wk = (const float*)d_in[3];
  const float* bk = (const float*)d_in[4];
  const float* Wv = (const float*)d_in[5];
  const float* bv = (const float*)d_in[6];
  const float* Wo = (const float*)d_in[7];
  const float* bo = (const float*)d_in[8];
  float* out = (float*)d_out;
  (void)n_in; (void)in_sizes; (void)out_size;

  PLA pla;
  build_pla(pla);

  const size_t NX = 8 * 512 * 768;   // 3145728
  const size_t NW = 768 * 768;       // 589824
  const size_t Q15_BYTES = 3072ull * 16384;  // 48 MiB

  uint8_t* ws = (uint8_t*)d_ws;
  size_t off = 0;
  auto alloc = [&](size_t bytes) -> void* {
    void* p = ws + off;
    off += (bytes + 255) & ~(size_t)255;
    return p;
  };

  unsigned* scal = (unsigned*)alloc(256);
  int8_t* qWq = (int8_t*)alloc(NW);
  int8_t* qWk = (int8_t*)alloc(NW);
  int8_t* qWv = (int8_t*)alloc(NW);
  int8_t* qWo = (int8_t*)alloc(NW);
  float* qbq = (float*)alloc(768 * 4);
  float* qbk = (float*)alloc(768 * 4);
  float* qbv = (float*)alloc(768 * 4);
  float* qbo = (float*)alloc(768 * 4);
  int8_t* qX = (int8_t*)alloc(NX);       // reused as i1
  int8_t* i1 = qX;

  size_t fixed = off;
  size_t need_fast = fixed + Q15_BYTES + (4 * NX) + NX + 512;
  bool fast = ws_size >= need_fast;

  hipMemsetAsync(scal, 0, 256, stream);

  if (fast) {
    uint8_t* D = (uint8_t*)alloc(Q15_BYTES);        // Yq|Yk|Yv then q15
    float* Yq = (float*)D;
    float* Yk = (float*)(D + NX * 4);
    float* Yv = (float*)(D + 2 * NX * 4);
    int* q15buf = (int*)D;
    uint8_t* E = (uint8_t*)alloc(4 * NX);           // qq|qk then ctx
    int8_t* qq = (int8_t*)E;
    int8_t* qk = (int8_t*)(E + NX);
    float* ctx = (float*)E;
    int8_t* qvT = (int8_t*)alloc(NX);               // then qctx2
    int8_t* qctx2 = qvT;

    maxabs_all<<<1604, 256, 0, stream>>>((const float4*)X, (const float4*)Wq, (const float4*)Wk,
                                         (const float4*)Wv, (const float4*)Wo, bq, bk, bv, bo, scal);
    quant_all<<<1609, 256, 0, stream>>>((const float4*)X, (int*)qX,
                                        (const float4*)Wq, (const float4*)Wk, (const float4*)Wv, (const float4*)Wo,
                                        (int*)qWq, (int*)qWk, (int*)qWv, (int*)qWo,
                                        bq, bk, bv, qbq, qbk, qbv, scal);
    gemm_qkv<<<dim3(12, 32, 3), 256, 0, stream>>>(qX, qWq, qWk, qWv, qbq, qbk, qbv, Yq, Yk, Yv, scal);
    quant_heads_all<<<6912, 256, 0, stream>>>(Yq, (int*)qq, Yk, (int*)qk, Yv, qvT, scal);
    attn_pass1<<<3072, 256, 0, stream>>>(qq, qk, q15buf, scal, pla);
    attn_pass2_load<<<3072, 256, 0, stream>>>(q15buf, qvT, scal, ctx, pla);
    ctx_q1_kernel<<<3072, 256, 0, stream>>>((const float4*)ctx, (int*)i1, scal);
    ctx_q2_plus<<<3075, 256, 0, stream>>>((const int*)i1, (int*)qctx2, bo, qbo, scal);
    gemm_proj<<<dim3(12, 32), 256, 0, stream>>>(qctx2, qWo, out, qbo, scal, S_CTXQ1, S_WO, -1);
  } else {
    float* Y = (float*)alloc(NX * 4);               // then ctx
    float* ctx = Y;
    int8_t* qq = (int8_t*)alloc(NX);                // then qctx2
    int8_t* qctx2 = qq;
    int8_t* qk = (int8_t*)alloc(NX);
    int8_t* qvT = (int8_t*)alloc(NX);

    maxabs_all<<<1604, 256, 0, stream>>>((const float4*)X, (const float4*)Wq, (const float4*)Wk,
                                         (const float4*)Wv, (const float4*)Wo, bq, bk, bv, bo, scal);
    quant_all<<<1609, 256, 0, stream>>>((const float4*)X, (int*)qX,
                                        (const float4*)Wq, (const float4*)Wk, (const float4*)Wv, (const float4*)Wo,
                                        (int*)qWq, (int*)qWk, (int*)qWv, (int*)qWo,
                                        bq, bk, bv, qbq, qbk, qbv, scal);
    gemm_proj<<<dim3(12, 32), 256, 0, stream>>>(qX, qWq, Y, qbq, scal, S_X, S_WQ, S_YQ);
    quant_heads_qk<<<3072, 256, 0, stream>>>(Y, (int*)qq, scal, S_YQ);
    gemm_proj<<<dim3(12, 32), 256, 0, stream>>>(qX, qWk, Y, qbk, scal, S_X, S_WK, S_YK);
    quant_heads_qk<<<3072, 256, 0, stream>>>(Y, (int*)qk, scal, S_YK);
    gemm_proj<<<dim3(12, 32), 256, 0, stream>>>(qX, qWv, Y, qbv, scal, S_X, S_WV, S_YV);
    quant_heads_v<<<768, 256, 0, stream>>>(Y, qvT, scal);
    attn_pass1<<<3072, 256, 0, stream>>>(qq, qk, (int*)nullptr, scal, pla);
    attn_pass2_recompute<<<3072, 256, 0, stream>>>(qq, qk, qvT, scal, ctx, pla);
    ctx_q1_kernel<<<3072, 256, 0, stream>>>((const float4*)ctx, (int*)i1, scal);
    ctx_q2_plus<<<3075, 256, 0, stream>>>((const int*)i1, (int*)qctx2, bo, qbo, scal);
    gemm_proj<<<dim3(12, 32), 256, 0, stream>>>(qctx2, qWo, out, qbo, scal, S_CTXQ1, S_WO, -1);
  }
}

// Round 6
// 210.691 us; speedup vs baseline: 5.6925x; 1.0129x over previous
//
#include <hip/hip_runtime.h>
#include <cstdint>
#include <cmath>
#include <cstddef>

#pragma clang fp contract(off)

#define QMAXF 127.0f

typedef int i32x4 __attribute__((ext_vector_type(4)));

enum {
  S_X = 0, S_WQ, S_WK, S_WV, S_WO, S_BQ, S_BK, S_BV, S_BO,
  S_YQ, S_YK, S_YV, S_CTX, S_CTXQ1, S_DMIN, S_COUNT
};

struct PLA { float m[12]; float c[12]; float a[12]; };

#define GLOAD_LDS16(gsrc, ldst) \
  __builtin_amdgcn_global_load_lds((const __attribute__((address_space(1))) void*)(gsrc), \
                                   (__attribute__((address_space(3))) void*)(ldst), 16, 0, 0)

// ---------------- device helpers ----------------

__device__ __forceinline__ float qscale(const unsigned* scal, int slot) {
  // reference: scale = max(maxabs / 127.0, 1e-8)
  return fmaxf(__uint_as_float(scal[slot]) / QMAXF, 1e-8f);
}

// Markstein correctly-rounded division with hoisted refined reciprocal.
// refined_rcp: v_rcp (1ulp) + 1 Newton step via fma -> ~0.5ulp reciprocal.
// fdiv_m: q0=v*rd; r=fma(-d,q0,v); q=fma(r,rd,q0) -> correctly-rounded quotient
// for normal operands (our ranges: d in [1,520] or sp in [1e-8,1], v in [0,1.1e5]).
__device__ __forceinline__ float refined_rcp(float d) {
  float rd = __builtin_amdgcn_rcpf(d);
  return fmaf(fmaf(-d, rd, 1.0f), rd, rd);
}
__device__ __forceinline__ float fdiv_m(float v, float d, float rd) {
  float q0 = v * rd;
  float r = fmaf(-d, q0, v);
  return fmaf(r, rd, q0);
}

__device__ __forceinline__ void block_atomic_maxf(float v, unsigned* slot) {
  for (int off = 32; off > 0; off >>= 1) v = fmaxf(v, __shfl_xor(v, off, 64));
  __shared__ float red[4];
  int lane = threadIdx.x & 63, w = threadIdx.x >> 6;
  if (lane == 0) red[w] = v;
  __syncthreads();
  if (threadIdx.x == 0)
    atomicMax(slot, __float_as_uint(fmaxf(fmaxf(red[0], red[1]), fmaxf(red[2], red[3]))));
}

__device__ __forceinline__ int qpack4(float a0, float a1, float a2, float a3, float s) {
  int i0 = (int)fminf(fmaxf(rintf(a0 / s), -QMAXF), QMAXF);
  int i1 = (int)fminf(fmaxf(rintf(a1 / s), -QMAXF), QMAXF);
  int i2 = (int)fminf(fmaxf(rintf(a2 / s), -QMAXF), QMAXF);
  int i3 = (int)fminf(fmaxf(rintf(a3 / s), -QMAXF), QMAXF);
  return (i0 & 255) | ((i1 & 255) << 8) | ((i2 & 255) << 16) | ((i3 & 255) << 24);
}

__device__ __forceinline__ float fabs4max(float4 v) {
  return fmaxf(fmaxf(fabsf(v.x), fabsf(v.y)), fmaxf(fabsf(v.z), fabsf(v.w)));
}

// ---------------- fused maxabs: X + 4 weights + 4 biases, one launch ----------------

__global__ __launch_bounds__(256) void maxabs_all(const float4* __restrict__ X,
                                                  const float4* __restrict__ w0, const float4* __restrict__ w1,
                                                  const float4* __restrict__ w2, const float4* __restrict__ w3,
                                                  const float* __restrict__ b0, const float* __restrict__ b1,
                                                  const float* __restrict__ b2, const float* __restrict__ b3,
                                                  unsigned* __restrict__ scal) {
  int blk = blockIdx.x, t = threadIdx.x;
  float m = 0.0f;
  unsigned* slot;
  if (blk < 1024) {
    int i = blk * 256 + t;
#pragma unroll
    for (int k = 0; k < 3; ++k) m = fmaxf(m, fabs4max(X[i + k * 262144]));
    slot = scal + S_X;
  } else if (blk < 1600) {
    int which = (blk - 1024) / 144, j = (blk - 1024) % 144;
    const float4* p = which == 0 ? w0 : which == 1 ? w1 : which == 2 ? w2 : w3;
    int i = j * 256 + t;
#pragma unroll
    for (int k = 0; k < 4; ++k) m = fmaxf(m, fabs4max(p[i + k * 36864]));
    slot = scal + S_WQ + which;
  } else {
    int which = blk - 1600;
    const float* p = which == 0 ? b0 : which == 1 ? b1 : which == 2 ? b2 : b3;
    for (int i = t; i < 768; i += 256) m = fmaxf(m, fabsf(p[i]));
    slot = scal + S_BQ + which;
  }
  block_atomic_maxf(m, slot);
}

// ---------------- fused quant: X + 4 weights + qbias(q,k,v) ----------------

__device__ __forceinline__ void qbias_body(const float* __restrict__ b, float* __restrict__ qb,
                                           const unsigned* __restrict__ scal, int slotX, int slotW, int slotB, int j) {
  if (j >= 768) return;
  float in_scale = __uint_as_float(scal[slotX]) / QMAXF;   // no clamp (reference)
  float w_scale  = __uint_as_float(scal[slotW]) / QMAXF;
  float bias_scale = in_scale * w_scale;
  float tmax = __uint_as_float(scal[slotB]) / bias_scale;
  float st = fmaxf(tmax / QMAXF, 1e-8f);
  float t = b[j] / bias_scale;
  float qv = fminf(fmaxf(rintf(t / st), -127.0f), 127.0f) * st;
  qb[j] = qv * bias_scale;
}

__global__ __launch_bounds__(256) void quant_all(const float4* __restrict__ X, int* __restrict__ qX,
                                                 const float4* __restrict__ w0, const float4* __restrict__ w1,
                                                 const float4* __restrict__ w2, const float4* __restrict__ w3,
                                                 int* __restrict__ o0, int* __restrict__ o1,
                                                 int* __restrict__ o2, int* __restrict__ o3,
                                                 const float* __restrict__ bq, const float* __restrict__ bk,
                                                 const float* __restrict__ bv,
                                                 float* __restrict__ qbq, float* __restrict__ qbk,
                                                 float* __restrict__ qbv,
                                                 const unsigned* __restrict__ scal) {
  int blk = blockIdx.x, t = threadIdx.x;
  if (blk < 1024) {
    float s = qscale(scal, S_X);
    int i = blk * 256 + t;
#pragma unroll
    for (int k = 0; k < 3; ++k) {
      float4 v = X[i + k * 262144];
      qX[i + k * 262144] = qpack4(v.x, v.y, v.z, v.w, s);
    }
  } else if (blk < 1600) {
    int which = (blk - 1024) / 144, j = (blk - 1024) % 144;
    const float4* p = which == 0 ? w0 : which == 1 ? w1 : which == 2 ? w2 : w3;
    int* o = which == 0 ? o0 : which == 1 ? o1 : which == 2 ? o2 : o3;
    float s = qscale(scal, S_WQ + which);
    int i = j * 256 + t;
#pragma unroll
    for (int k = 0; k < 4; ++k) {
      float4 v = p[i + k * 36864];
      o[i + k * 36864] = qpack4(v.x, v.y, v.z, v.w, s);
    }
  } else {
    int proj = (blk - 1600) / 3, part = (blk - 1600) % 3;
    int j = part * 256 + t;
    const float* b = proj == 0 ? bq : proj == 1 ? bk : bv;
    float* qb = proj == 0 ? qbq : proj == 1 ? qbk : qbv;
    qbias_body(b, qb, scal, S_X, S_WQ + proj, S_BQ + proj, j);
  }
}

// ---------------- LDS-staged MFMA int8 GEMM (proven R5 structure) ----------------

__device__ __forceinline__ void gemm_body(const int8_t* __restrict__ A, const int8_t* __restrict__ Bm,
                                          float* __restrict__ C, const float* __restrict__ bias,
                                          unsigned* __restrict__ scal, int slotA, int slotB, int maxslot) {
  __shared__ int8_t Al[16384];   // [128 rows][128 K-bytes], row r holds A[r][col ^ ((r&7)<<4)]
  __shared__ int8_t Bl[8192];    // [64 rows][128 K-bytes]
  int t = threadIdx.x, lane = t & 63, w = t >> 6, l15 = lane & 15, kg4 = lane >> 4;
  int bm = blockIdx.y * 128, bn = blockIdx.x * 64;
  float sAB = qscale(scal, slotA) * qscale(scal, slotB);
  int srow = t >> 3, scol = (t & 7) * 16;
  int ssw = scol ^ ((srow & 7) << 4);
  i32x4 acc[2][4];
#pragma unroll
  for (int rt = 0; rt < 2; ++rt)
#pragma unroll
    for (int ct = 0; ct < 4; ++ct)
#pragma unroll
      for (int r = 0; r < 4; ++r) acc[rt][ct][r] = 0;

  for (int kt = 0; kt < 6; ++kt) {
    int kc = kt * 128;
#pragma unroll
    for (int j = 0; j < 4; ++j) {
      int r = j * 32 + srow;
      GLOAD_LDS16(A + (size_t)(bm + r) * 768 + kc + ssw, Al + r * 128 + scol);
    }
#pragma unroll
    for (int j = 0; j < 2; ++j) {
      int r = j * 32 + srow;
      GLOAD_LDS16(Bm + (size_t)(bn + r) * 768 + kc + ssw, Bl + r * 128 + scol);
    }
    __syncthreads();
#pragma unroll
    for (int kg = 0; kg < 2; ++kg) {
      int kcol = kg * 64 + kg4 * 16;
      i32x4 af[2], bf[4];
#pragma unroll
      for (int rt = 0; rt < 2; ++rt) {
        int ar = w * 32 + rt * 16 + l15;
        af[rt] = *(const i32x4*)(Al + ar * 128 + (kcol ^ ((ar & 7) << 4)));
      }
#pragma unroll
      for (int ct = 0; ct < 4; ++ct) {
        int br = ct * 16 + l15;
        bf[ct] = *(const i32x4*)(Bl + br * 128 + (kcol ^ ((br & 7) << 4)));
      }
#pragma unroll
      for (int rt = 0; rt < 2; ++rt)
#pragma unroll
        for (int ct = 0; ct < 4; ++ct)
          acc[rt][ct] = __builtin_amdgcn_mfma_i32_16x16x64_i8(af[rt], bf[ct], acc[rt][ct], 0, 0, 0);
    }
    __syncthreads();
  }
  float am = 0.0f;
#pragma unroll
  for (int rt = 0; rt < 2; ++rt)
#pragma unroll
    for (int ct = 0; ct < 4; ++ct) {
      int col = bn + ct * 16 + l15;
      float bv = bias[col];
#pragma unroll
      for (int r = 0; r < 4; ++r) {
        int row = bm + w * 32 + rt * 16 + kg4 * 4 + r;   // C/D: col=lane&15, row=(lane>>4)*4+reg
        float v = (float)acc[rt][ct][r] * sAB;
        float yv = v + bv;
        C[(size_t)row * 768 + col] = yv;
        am = fmaxf(am, fabsf(yv));
      }
    }
  if (maxslot >= 0) block_atomic_maxf(am, scal + maxslot);
}

__global__ __launch_bounds__(256) void gemm_qkv(const int8_t* __restrict__ qX,
                                                const int8_t* __restrict__ qWq, const int8_t* __restrict__ qWk,
                                                const int8_t* __restrict__ qWv,
                                                const float* __restrict__ qbq, const float* __restrict__ qbk,
                                                const float* __restrict__ qbv,
                                                float* __restrict__ Yq, float* __restrict__ Yk, float* __restrict__ Yv,
                                                unsigned* __restrict__ scal) {
  int z = blockIdx.z;
  const int8_t* Bm = z == 0 ? qWq : z == 1 ? qWk : qWv;
  const float* bias = z == 0 ? qbq : z == 1 ? qbk : qbv;
  float* C = z == 0 ? Yq : z == 1 ? Yk : Yv;
  gemm_body(qX, Bm, C, bias, scal, S_X, S_WQ + z, S_YQ + z);
}

__global__ __launch_bounds__(256) void gemm_proj(const int8_t* __restrict__ A, const int8_t* __restrict__ Bm,
                                                 float* __restrict__ C, const float* __restrict__ bias,
                                                 unsigned* __restrict__ scal, int slotA, int slotB, int maxslot) {
  gemm_body(A, Bm, C, bias, scal, slotA, slotB, maxslot);
}

// ---------------- head re-layout + quant ----------------

__device__ __forceinline__ void qheads_qk_body(const float* __restrict__ Y, int* __restrict__ q,
                                               const unsigned* __restrict__ scal, int slot, int i) {
  float s = qscale(scal, slot);
  int d0 = (i & 15) * 4;
  int sI = (i >> 4) & 511;
  int bh = i >> 13;
  int h = bh % 12, b = bh / 12;
  const float* src = Y + ((size_t)(b * 512 + sI)) * 768 + h * 64 + d0;
  float4 v = *(const float4*)src;
  q[i] = qpack4(v.x, v.y, v.z, v.w, s);
}

__device__ __forceinline__ void qheads_v_body(const float* __restrict__ Y, int8_t* __restrict__ q,
                                              const unsigned* __restrict__ scal, int blkv) {
  __shared__ int8_t T[64][68];
  int bh = blkv >> 3, sb = blkv & 7;
  int b = bh / 12, h = bh % 12;
  float s = qscale(scal, S_YV);
  int d = threadIdx.x & 63, sl = threadIdx.x >> 6;
#pragma unroll
  for (int i = 0; i < 16; ++i) {
    int s_local = i * 4 + sl;
    float y = Y[((size_t)(b * 512 + sb * 64 + s_local)) * 768 + h * 64 + d];
    float tq = fminf(fmaxf(rintf(y / s), -QMAXF), QMAXF);
    T[d][s_local] = (int8_t)tq;
  }
  __syncthreads();
  int s4 = (threadIdx.x & 15) * 4, dl = threadIdx.x >> 4;
#pragma unroll
  for (int i = 0; i < 4; ++i) {
    int d_ = i * 16 + dl;
    int packed = (T[d_][s4] & 255) | ((T[d_][s4 + 1] & 255) << 8) |
                 ((T[d_][s4 + 2] & 255) << 16) | ((T[d_][s4 + 3] & 255) << 24);
    *(int*)(q + (size_t)bh * 32768 + (size_t)d_ * 512 + sb * 64 + s4) = packed;
  }
}

__global__ __launch_bounds__(256) void quant_heads_all(const float* __restrict__ Yq, int* __restrict__ qq,
                                                       const float* __restrict__ Yk, int* __restrict__ qk,
                                                       const float* __restrict__ Yv, int8_t* __restrict__ qvT,
                                                       const unsigned* __restrict__ scal) {
  int blk = blockIdx.x;
  if (blk < 3072)      qheads_qk_body(Yq, qq, scal, S_YQ, blk * 256 + threadIdx.x);
  else if (blk < 6144) qheads_qk_body(Yk, qk, scal, S_YK, (blk - 3072) * 256 + threadIdx.x);
  else                 qheads_v_body(Yv, qvT, scal, blk - 6144);
}

__global__ __launch_bounds__(256) void quant_heads_qk(const float* __restrict__ Y, int* __restrict__ q,
                                                      const unsigned* __restrict__ scal, int slot) {
  qheads_qk_body(Y, q, scal, slot, blockIdx.x * 256 + threadIdx.x);
}
__global__ __launch_bounds__(256) void quant_heads_v(const float* __restrict__ Y, int8_t* __restrict__ q,
                                                     const unsigned* __restrict__ scal) {
  qheads_v_body(Y, q, scal, blockIdx.x);
}

// ---------------- attention: swapped QK^T + register softmax + LDS PLA lookup ----------------
// Q32.26 snap streamlined: clamp in scaled-int domain (identical to snap-then-clamp:
// -10*2^26 = -671088640 exact; scaling by 2^-26 exact).
// Interval idx: arithmetic estimate + exact +-1 correction vs f32 edge pair (one b64 read)
// == clip(searchsorted(PLA_A, xc, 'right')-1, 0, 10) exactly.

__device__ __forceinline__ void attn_e_phase(const int8_t* __restrict__ qbase,
                                             const int8_t* __restrict__ kbase,
                                             int rb, float pref, const PLA& pla,
                                             float (&v)[8][4], float (*red)[16], float& denom) {
  __shared__ float2 ae2[11];   // (a[i], a[i+1])
  __shared__ float2 mcs[11];   // (m[i], c[i])
  int t = threadIdx.x, lane = t & 63, w = t >> 6, l15 = lane & 15, kg = lane >> 4;
  if (t < 11) {
    ae2[t] = make_float2(pla.a[t], pla.a[t + 1]);
    mcs[t] = make_float2(pla.m[t], pla.c[t]);
  }
  i32x4 zero = {0, 0, 0, 0};
  i32x4 qf = *(const i32x4*)(qbase + (size_t)(rb * 16 + l15) * 64 + kg * 16);
  i32x4 acc[8];
#pragma unroll
  for (int i = 0; i < 8; ++i) {
    i32x4 kf = *(const i32x4*)(kbase + (size_t)((w * 8 + i) * 16 + l15) * 64 + kg * 16);
    acc[i] = __builtin_amdgcn_mfma_i32_16x16x64_i8(kf, qf, zero, 0, 0, 0);
  }
  float mx = -3.4e38f;
#pragma unroll
  for (int i = 0; i < 8; ++i)
#pragma unroll
    for (int r = 0; r < 4; ++r) {
      v[i][r] = (float)acc[i][r] * pref;
      mx = fmaxf(mx, v[i][r]);
    }
  mx = fmaxf(mx, __shfl_xor(mx, 16, 64));
  mx = fmaxf(mx, __shfl_xor(mx, 32, 64));
  if (lane < 16) red[w][l15] = mx;
  __syncthreads();                     // also covers ae2/mcs init
  float gm = fmaxf(fmaxf(red[0][l15], red[1][l15]), fmaxf(red[2][l15], red[3][l15]));
  __syncthreads();
  float s = 0.0f;
#pragma unroll
  for (int i = 0; i < 8; ++i)
#pragma unroll
    for (int r = 0; r < 4; ++r) {
      float x = v[i][r] - gm;
      float sh = rintf(x * 67108864.0f);
      sh = fmaxf(sh, -671088640.0f);
      sh = fminf(sh, 0.0f);
      float xc = sh * (1.0f / 67108864.0f);
      float tf = (xc + 10.0f) * 1.2f;
      int i0 = (int)tf;
      i0 = i0 > 10 ? 10 : i0;
      float2 ee = ae2[i0];
      int idx = i0 + ((i0 < 10 && xc >= ee.y) ? 1 : 0) - ((xc < ee.x) ? 1 : 0);
      float2 mc = mcs[idx];
      float e = mc.x * xc;   // no fma: contract off
      e = e + mc.y;
      v[i][r] = e;
      s += e;
    }
  s += __shfl_xor(s, 16, 64);
  s += __shfl_xor(s, 32, 64);
  if (lane < 16) red[w][l15] = s;
  __syncthreads();
  denom = (((red[0][l15] + red[1][l15]) + red[2][l15]) + red[3][l15]) + 1e-9f;
}

// pass1: e-phase ONCE; stores exact q15 ints. pmax derives from denom_min (row-max e == c[10]).
// q15 = rint((v*32768)/denom): *2^15 exact, so == rint((v/denom)*32768); division via
// hoisted-Markstein (denom per-lane constant).
__global__ __launch_bounds__(256) void attn_pass1(const int8_t* __restrict__ qq,
                                                  const int8_t* __restrict__ qk,
                                                  int* __restrict__ q15w,
                                                  unsigned* __restrict__ scal, PLA pla) {
  __shared__ float red[4][16];
  int rb = blockIdx.x & 31, bh = blockIdx.x >> 5;
  float pref = (qscale(scal, S_YQ) * qscale(scal, S_YK)) * 0.125f;
  float v[8][4];
  float denom;
  attn_e_phase(qq + (size_t)bh * 32768, qk + (size_t)bh * 32768, rb, pref, pla, v, red, denom);
  int t = threadIdx.x;
  if (q15w) {
    float rdn = refined_rcp(denom);
    int base = blockIdx.x * 4096;
#pragma unroll
    for (int i = 0; i < 8; ++i) {
      int q15i[4];
#pragma unroll
      for (int r = 0; r < 4; ++r) {
        float sm32 = fdiv_m(v[i][r] * 32768.0f, denom, rdn);
        float q15 = fminf(fmaxf(rintf(sm32), -32768.0f), 32767.0f);
        q15i[r] = (int)q15;
      }
      q15w[base + (i * 2 + 0) * 256 + t] = (q15i[0] & 0xffff) | (q15i[1] << 16);
      q15w[base + (i * 2 + 1) * 256 + t] = (q15i[2] & 0xffff) | (q15i[3] << 16);
    }
  }
  if (t < 64) {
    float dm = denom;
    dm = fminf(dm, __shfl_xor(dm, 1, 64));
    dm = fminf(dm, __shfl_xor(dm, 2, 64));
    dm = fminf(dm, __shfl_xor(dm, 4, 64));
    dm = fminf(dm, __shfl_xor(dm, 8, 64));
    if (t == 0) atomicMax(scal + S_DMIN, 0x7f800000u - __float_as_uint(dm));
  }
}

__device__ __forceinline__ float derive_sp(const unsigned* scal, const PLA& pla) {
  float dmin = __uint_as_float(0x7f800000u - scal[S_DMIN]);
  float smm = pla.c[10] / dmin;
  float q15m = fminf(fmaxf(rintf(smm * 32768.0f), -32768.0f), 32767.0f);
  return fmaxf((q15m * (1.0f / 32768.0f)) / QMAXF, 1e-8f);
}

__device__ __forceinline__ void attn_pv_tail(const int8_t* __restrict__ vT, int8_t (*Ps)[528],
                                             unsigned* __restrict__ scal, float* __restrict__ ctx,
                                             int rb, int bh, float sp) {
  int t = threadIdx.x, lane = t & 63, w = t >> 6, l15 = lane & 15, kg = lane >> 4;
  int b = bh / 12, h = bh % 12;
  float sv = qscale(scal, S_YV);
  i32x4 pacc = {0, 0, 0, 0};
  const int8_t* vbase = vT + (size_t)bh * 32768 + (size_t)(w * 16 + l15) * 512;
#pragma unroll
  for (int ks = 0; ks < 8; ++ks) {
    i32x4 pf = *(const i32x4*)&Ps[l15][ks * 64 + kg * 16];
    i32x4 vf = *(const i32x4*)(vbase + ks * 64 + kg * 16);
    pacc = __builtin_amdgcn_mfma_i32_16x16x64_i8(pf, vf, pacc, 0, 0, 0);
  }
  float spv = sp * sv;
  float am = 0.0f;
#pragma unroll
  for (int r = 0; r < 4; ++r) {
    int srow = rb * 16 + kg * 4 + r;
    float val = (float)pacc[r] * spv;
    ctx[((size_t)(b * 512 + srow)) * 768 + h * 64 + w * 16 + l15] = val;
    am = fmaxf(am, fabsf(val));
  }
  block_atomic_maxf(am, scal + S_CTX);
}

__global__ __launch_bounds__(256) void attn_pass2_load(const int* __restrict__ q15r,
                                                       const int8_t* __restrict__ vT,
                                                       unsigned* __restrict__ scal,
                                                       float* __restrict__ ctx, PLA pla) {
  __shared__ alignas(16) int8_t Ps[16][528];
  int rb = blockIdx.x & 31, bh = blockIdx.x >> 5;
  float sp = derive_sp(scal, pla);
  float rsp = refined_rcp(sp);
  int t = threadIdx.x, lane = t & 63, w = t >> 6, l15 = lane & 15, kg = lane >> 4;
  int base = blockIdx.x * 4096;
#pragma unroll
  for (int i = 0; i < 8; ++i) {
    int u01 = q15r[base + (i * 2 + 0) * 256 + t];
    int u23 = q15r[base + (i * 2 + 1) * 256 + t];
    int q15i[4] = { (int)(short)(u01 & 0xffff), u01 >> 16,
                    (int)(short)(u23 & 0xffff), u23 >> 16 };
    uint32_t packed = 0;
#pragma unroll
    for (int r = 0; r < 4; ++r) {
      float pv = (float)q15i[r] * (1.0f / 32768.0f);
      int qp = (int)fminf(fmaxf(rintf(fdiv_m(pv, sp, rsp)), -QMAXF), QMAXF);
      packed |= (uint32_t)(qp & 255) << (8 * r);
    }
    *(uint32_t*)&Ps[l15][(w * 8 + i) * 16 + kg * 4] = packed;
  }
  __syncthreads();
  attn_pv_tail(vT, Ps, scal, ctx, rb, bh, sp);
}

__global__ __launch_bounds__(256) void attn_pass2_recompute(const int8_t* __restrict__ qq,
                                                            const int8_t* __restrict__ qk,
                                                            const int8_t* __restrict__ vT,
                                                            unsigned* __restrict__ scal,
                                                            float* __restrict__ ctx, PLA pla) {
  __shared__ float red[4][16];
  __shared__ alignas(16) int8_t Ps[16][528];
  int rb = blockIdx.x & 31, bh = blockIdx.x >> 5;
  float pref = (qscale(scal, S_YQ) * qscale(scal, S_YK)) * 0.125f;
  float sp = derive_sp(scal, pla);
  float rsp = refined_rcp(sp);
  float v[8][4];
  float denom;
  attn_e_phase(qq + (size_t)bh * 32768, qk + (size_t)bh * 32768, rb, pref, pla, v, red, denom);
  float rdn = refined_rcp(denom);
  int t = threadIdx.x, lane = t & 63, w = t >> 6, l15 = lane & 15, kg = lane >> 4;
#pragma unroll
  for (int i = 0; i < 8; ++i) {
    uint32_t packed = 0;
#pragma unroll
    for (int r = 0; r < 4; ++r) {
      float sm32 = fdiv_m(v[i][r] * 32768.0f, denom, rdn);
      float q15 = fminf(fmaxf(rintf(sm32), -32768.0f), 32767.0f);
      float pv = q15 * (1.0f / 32768.0f);
      int qp = (int)fminf(fmaxf(rintf(fdiv_m(pv, sp, rsp)), -QMAXF), QMAXF);
      packed |= (uint32_t)(qp & 255) << (8 * r);
    }
    *(uint32_t*)&Ps[l15][(w * 8 + i) * 16 + kg * 4] = packed;
  }
  __syncthreads();
  attn_pv_tail(vT, Ps, scal, ctx, rb, bh, sp);
}

// ---------------- ctx double-quant (exact IEEE divisions kept: cheap kernels) ----------------

__global__ __launch_bounds__(256) void ctx_q1_kernel(const float4* __restrict__ ctx, int* __restrict__ i1,
                                                     unsigned* __restrict__ scal) {
  int i = blockIdx.x * 256 + threadIdx.x;
  float s1 = qscale(scal, S_CTX);
  float4 c = ctx[i];
  int q0 = (int)fminf(fmaxf(rintf(c.x / s1), -QMAXF), QMAXF);
  int q1 = (int)fminf(fmaxf(rintf(c.y / s1), -QMAXF), QMAXF);
  int q2 = (int)fminf(fmaxf(rintf(c.z / s1), -QMAXF), QMAXF);
  int q3 = (int)fminf(fmaxf(rintf(c.w / s1), -QMAXF), QMAXF);
  i1[i] = (q0 & 255) | ((q1 & 255) << 8) | ((q2 & 255) << 16) | ((q3 & 255) << 24);
  float am = fmaxf(fmaxf(fabsf((float)q0 * s1), fabsf((float)q1 * s1)),
                   fmaxf(fabsf((float)q2 * s1), fabsf((float)q3 * s1)));
  block_atomic_maxf(am, scal + S_CTXQ1);
}

__global__ __launch_bounds__(256) void ctx_q2_plus(const int* __restrict__ i1, int* __restrict__ q2o,
                                                   const float* __restrict__ bo, float* __restrict__ qbo,
                                                   const unsigned* __restrict__ scal) {
  int blk = blockIdx.x;
  if (blk < 3072) {
    int i = blk * 256 + threadIdx.x;
    float s1 = qscale(scal, S_CTX);
    float s2 = qscale(scal, S_CTXQ1);
    int v = i1[i];
    int out = 0;
#pragma unroll
    for (int k = 0; k < 4; ++k) {
      float y = (float)((int8_t)(v >> (8 * k))) * s1;
      int qq = (int)fminf(fmaxf(rintf(y / s2), -QMAXF), QMAXF);
      out |= (qq & 255) << (8 * k);
    }
    q2o[i] = out;
  } else {
    int j = (blk - 3072) * 256 + threadIdx.x;
    qbias_body(bo, qbo, scal, S_CTXQ1, S_WO, S_BO, j);
  }
}

// ---------------- host: PLA build (replicates np.polyfit degree-1 LS in f64) ----------------

static void build_pla(PLA& p) {
  double xs[1001], ys[1001];
  double step = 10.0 / 1000.0;
  for (int j = 0; j <= 1000; ++j) xs[j] = (double)j * step + (-10.0);
  xs[1000] = 0.0;
  for (int j = 0; j <= 1000; ++j) ys[j] = exp(xs[j]);
  double estep = 10.0 / 12.0;
  for (int i = 0; i < 12; ++i) {
    double a = (double)i * estep + (-10.0);
    double bb = (i + 1 == 12) ? 0.0 : (double)(i + 1) * estep + (-10.0);
    double n = 0, Sx = 0, Sy = 0, Sxx = 0, Sxy = 0;
    for (int j = 0; j <= 1000; ++j) {
      if (xs[j] >= a && xs[j] <= bb) {
        double x = xs[j], y = ys[j];
        n += 1.0; Sx += x; Sy += y; Sxx += x * x; Sxy += x * y;
      }
    }
    double det = n * Sxx - Sx * Sx;
    p.m[i] = (float)((n * Sxy - Sx * Sy) / det);
    p.c[i] = (float)((Sxx * Sy - Sx * Sxy) / det);
    p.a[i] = (float)a;
  }
}

// ---------------- launch ----------------

extern "C" void kernel_launch(void* const* d_in, const int* in_sizes, int n_in,
                              void* d_out, int out_size, void* d_ws, size_t ws_size,
                              hipStream_t stream) {
  const float* X  = (const float*)d_in[0];
  const float* Wq = (const float*)d_in[1];
  const float* bq = (const float*)d_in[2];
  const float* Wk = (const float*)d_in[3];
  const float* bk = (const float*)d_in[4];
  const float* Wv = (const float*)d_in[5];
  const float* bv = (const float*)d_in[6];
  const float* Wo = (const float*)d_in[7];
  const float* bo = (const float*)d_in[8];
  float* out = (float*)d_out;
  (void)n_in; (void)in_sizes; (void)out_size;

  PLA pla;
  build_pla(pla);

  const size_t NX = 8 * 512 * 768;   // 3145728
  const size_t NW = 768 * 768;       // 589824
  const size_t Q15_BYTES = 3072ull * 16384;  // 48 MiB

  uint8_t* ws = (uint8_t*)d_ws;
  size_t off = 0;
  auto alloc = [&](size_t bytes) -> void* {
    void* p = ws + off;
    off += (bytes + 255) & ~(size_t)255;
    return p;
  };

  unsigned* scal = (unsigned*)alloc(256);
  int8_t* qWq = (int8_t*)alloc(NW);
  int8_t* qWk = (int8_t*)alloc(NW);
  int8_t* qWv = (int8_t*)alloc(NW);
  int8_t* qWo = (int8_t*)alloc(NW);
  float* qbq = (float*)alloc(768 * 4);
  float* qbk = (float*)alloc(768 * 4);
  float* qbv = (float*)alloc(768 * 4);
  float* qbo = (float*)alloc(768 * 4);
  int8_t* qX = (int8_t*)alloc(NX);       // reused as i1
  int8_t* i1 = qX;

  size_t fixed = off;
  size_t need_fast = fixed + Q15_BYTES + (4 * NX) + NX + 512;
  bool fast = ws_size >= need_fast;

  hipMemsetAsync(scal, 0, 256, stream);

  if (fast) {
    uint8_t* D = (uint8_t*)alloc(Q15_BYTES);        // Yq|Yk|Yv then q15
    float* Yq = (float*)D;
    float* Yk = (float*)(D + NX * 4);
    float* Yv = (float*)(D + 2 * NX * 4);
    int* q15buf = (int*)D;
    uint8_t* E = (uint8_t*)alloc(4 * NX);           // qq|qk then ctx
    int8_t* qq = (int8_t*)E;
    int8_t* qk = (int8_t*)(E + NX);
    float* ctx = (float*)E;
    int8_t* qvT = (int8_t*)alloc(NX);               // then qctx2
    int8_t* qctx2 = qvT;

    maxabs_all<<<1604, 256, 0, stream>>>((const float4*)X, (const float4*)Wq, (const float4*)Wk,
                                         (const float4*)Wv, (const float4*)Wo, bq, bk, bv, bo, scal);
    quant_all<<<1609, 256, 0, stream>>>((const float4*)X, (int*)qX,
                                        (const float4*)Wq, (const float4*)Wk, (const float4*)Wv, (const float4*)Wo,
                                        (int*)qWq, (int*)qWk, (int*)qWv, (int*)qWo,
                                        bq, bk, bv, qbq, qbk, qbv, scal);
    gemm_qkv<<<dim3(12, 32, 3), 256, 0, stream>>>(qX, qWq, qWk, qWv, qbq, qbk, qbv, Yq, Yk, Yv, scal);
    quant_heads_all<<<6912, 256, 0, stream>>>(Yq, (int*)qq, Yk, (int*)qk, Yv, qvT, scal);
    attn_pass1<<<3072, 256, 0, stream>>>(qq, qk, q15buf, scal, pla);
    attn_pass2_load<<<3072, 256, 0, stream>>>(q15buf, qvT, scal, ctx, pla);
    ctx_q1_kernel<<<3072, 256, 0, stream>>>((const float4*)ctx, (int*)i1, scal);
    ctx_q2_plus<<<3075, 256, 0, stream>>>((const int*)i1, (int*)qctx2, bo, qbo, scal);
    gemm_proj<<<dim3(12, 32), 256, 0, stream>>>(qctx2, qWo, out, qbo, scal, S_CTXQ1, S_WO, -1);
  } else {
    float* Y = (float*)alloc(NX * 4);               // then ctx
    float* ctx = Y;
    int8_t* qq = (int8_t*)alloc(NX);                // then qctx2
    int8_t* qctx2 = qq;
    int8_t* qk = (int8_t*)alloc(NX);
    int8_t* qvT = (int8_t*)alloc(NX);

    maxabs_all<<<1604, 256, 0, stream>>>((const float4*)X, (const float4*)Wq, (const float4*)Wk,
                                         (const float4*)Wv, (const float4*)Wo, bq, bk, bv, bo, scal);
    quant_all<<<1609, 256, 0, stream>>>((const float4*)X, (int*)qX,
                                        (const float4*)Wq, (const float4*)Wk, (const float4*)Wv, (const float4*)Wo,
                                        (int*)qWq, (int*)qWk, (int*)qWv, (int*)qWo,
                                        bq, bk, bv, qbq, qbk, qbv, scal);
    gemm_proj<<<dim3(12, 32), 256, 0, stream>>>(qX, qWq, Y, qbq, scal, S_X, S_WQ, S_YQ);
    quant_heads_qk<<<3072, 256, 0, stream>>>(Y, (int*)qq, scal, S_YQ);
    gemm_proj<<<dim3(12, 32), 256, 0, stream>>>(qX, qWk, Y, qbk, scal, S_X, S_WK, S_YK);
    quant_heads_qk<<<3072, 256, 0, stream>>>(Y, (int*)qk, scal, S_YK);
    gemm_proj<<<dim3(12, 32), 256, 0, stream>>>(qX, qWv, Y, qbv, scal, S_X, S_WV, S_YV);
    quant_heads_v<<<768, 256, 0, stream>>>(Y, qvT, scal);
    attn_pass1<<<3072, 256, 0, stream>>>(qq, qk, (int*)nullptr, scal, pla);
    attn_pass2_recompute<<<3072, 256, 0, stream>>>(qq, qk, qvT, scal, ctx, pla);
    ctx_q1_kernel<<<3072, 256, 0, stream>>>((const float4*)ctx, (int*)i1, scal);
    ctx_q2_plus<<<3075, 256, 0, stream>>>((const int*)i1, (int*)qctx2, bo, qbo, scal);
    gemm_proj<<<dim3(12, 32), 256, 0, stream>>>(qctx2, qWo, out, qbo, scal, S_CTXQ1, S_WO, -1);
  }
}